// Round 1
// baseline (488.135 us; speedup 1.0000x reference)
//
#include <hip/hip_runtime.h>

#define N_B   32
#define CH    64
#define HW    32
#define HWHW  1024      // 32*32
#define CHW   65536     // 64*1024
#define NPIX  32768.0f  // N*H*W per channel
#define KDIM  576       // 64*3*3

// ---------------- prep: transpose weights [co][k] -> [k][co], zero stats ----
__global__ __launch_bounds__(256) void prep_kernel(
    const float* __restrict__ w1, const float* __restrict__ w2,
    float* __restrict__ wt1, float* __restrict__ wt2,
    float* __restrict__ stats) {
  int i = blockIdx.x * 256 + threadIdx.x;
  if (i < 256) stats[i] = 0.0f;
  if (i < CH * KDIM) {
    int co = i / KDIM, k = i % KDIM;
    wt1[k * CH + co] = w1[i];
    wt2[k * CH + co] = w2[i];
  }
}

// ---------------- adder2d + fused per-channel stats ----------------
// grid (8 cog, 2 ht, 32 n), block 256.
// Each thread: 8 output channels x 2 pixels (1 row x 2 cols).
// out[n,co,h,w] = -sum_{ci,kh,kw} |x[n,ci,h+kh-1,w+kw-1] - w[co,ci,kh,kw]|
__global__ __launch_bounds__(256) void adder_kernel(
    const float* __restrict__ xin,   // [32][64][32][32]
    const float* __restrict__ wt,    // [576][64] transposed weights
    float* __restrict__ out,         // [32][64][32][32]
    float* __restrict__ stats) {     // [0..63]=sum, [64..127]=sumsq
  const int cog = blockIdx.x;        // 0..7
  const int ht  = blockIdx.y;        // 0..1
  const int n   = blockIdx.z;        // 0..31
  const int tid = threadIdx.x;
  const int co0 = cog * 8;
  const int h0  = ht * 16;
  const int r   = tid >> 4;          // 0..15 (row in tile)
  const int c0  = (tid & 15) * 2;    // 0..30 (col pair)

  // x tile: 8 ci-planes, 18 rows (h0-1..h0+16), 34 used cols (col -1..32 at +1)
  // width 37 (odd) -> <=2-way LDS bank conflicts (free)
  __shared__ float xs[8][18][37];

  // zero-fill once: border cols/rows stay zero across all chunks
  {
    float* xsf = &xs[0][0][0];
    for (int i = tid; i < 8 * 18 * 37; i += 256) xsf[i] = 0.0f;
  }

  float acc[8][2];
#pragma unroll
  for (int co = 0; co < 8; ++co) { acc[co][0] = 0.0f; acc[co][1] = 0.0f; }

  const float* xb = xin + n * CHW;

  for (int cc = 0; cc < CH; cc += 8) {
    __syncthreads();  // zero-fill done (cc=0) / previous compute done (cc>0)
    // stage x[n][cc+ci][h0-1+row][0..31] -> xs[ci][row][1+col]
    // 8*18*8 = 1152 float4 loads
    for (int idx = tid; idx < 1152; idx += 256) {
      int ci  = idx / 144;           // 18*8
      int rem = idx - ci * 144;
      int row = rem >> 3;
      int c4  = rem & 7;
      int hr  = h0 - 1 + row;
      if (hr >= 0 && hr < HW) {
        const float4 v = *(const float4*)(xb + (cc + ci) * HWHW + hr * HW + c4 * 4);
        xs[ci][row][1 + c4 * 4 + 0] = v.x;
        xs[ci][row][1 + c4 * 4 + 1] = v.y;
        xs[ci][row][1 + c4 * 4 + 2] = v.z;
        xs[ci][row][1 + c4 * 4 + 3] = v.w;
      }
    }
    __syncthreads();

#pragma unroll
    for (int ci = 0; ci < 8; ++ci) {
#pragma unroll
      for (int kh = 0; kh < 3; ++kh) {
        float xv[4];
#pragma unroll
        for (int j = 0; j < 4; ++j) xv[j] = xs[ci][r + kh][c0 + j];
        // wave-uniform weight reads -> expect s_load_dwordx8
        const float* wp = wt + (((cc + ci) * 3 + kh) * 3) * CH + co0;
        float wv[3][8];
#pragma unroll
        for (int kw = 0; kw < 3; ++kw)
#pragma unroll
          for (int co = 0; co < 8; ++co) wv[kw][co] = wp[kw * CH + co];
#pragma unroll
        for (int kw = 0; kw < 3; ++kw) {
#pragma unroll
          for (int co = 0; co < 8; ++co) {
            acc[co][0] += __builtin_fabsf(xv[kw + 0] - wv[kw][co]);
            acc[co][1] += __builtin_fabsf(xv[kw + 1] - wv[kw][co]);
          }
        }
      }
    }
  }

  // epilogue: write outputs (negated), wave-reduce per-channel sum/sumsq, atomics
  const int lane  = tid & 63;
  const int obase = n * CHW + (h0 + r) * HW + c0;
#pragma unroll
  for (int co = 0; co < 8; ++co) {
    float v0 = -acc[co][0], v1 = -acc[co][1];
    float2 vv = make_float2(v0, v1);
    *(float2*)(out + obase + (co0 + co) * HWHW) = vv;
    float sm = v0 + v1;
    float sq = v0 * v0 + v1 * v1;
#pragma unroll
    for (int m = 1; m < 64; m <<= 1) {
      sm += __shfl_xor(sm, m);
      sq += __shfl_xor(sq, m);
    }
    if (lane == 0) {
      atomicAdd(stats + (co0 + co), sm);
      atomicAdd(stats + 64 + (co0 + co), sq);
    }
  }
}

// ---------------- BN (train-mode, stats given) + ReLU ----------------
__global__ __launch_bounds__(256) void bnrelu_kernel(
    const float* __restrict__ A, const float* __restrict__ stats,
    const float* __restrict__ g, const float* __restrict__ b,
    float* __restrict__ B) {
  int i = blockIdx.x * 256 + threadIdx.x;  // float4 index, 524288 total
  int c = (i >> 8) & 63;
  float mu  = stats[c] * (1.0f / NPIX);
  float var = fmaf(-mu, mu, stats[64 + c] * (1.0f / NPIX));
  float rs  = rsqrtf(var + 1e-5f);
  float ga  = g[c] * rs;
  float be  = fmaf(-mu, ga, b[c]);
  float4 v = ((const float4*)A)[i];
  v.x = fmaxf(fmaf(v.x, ga, be), 0.0f);
  v.y = fmaxf(fmaf(v.y, ga, be), 0.0f);
  v.z = fmaxf(fmaf(v.z, ga, be), 0.0f);
  v.w = fmaxf(fmaf(v.w, ga, be), 0.0f);
  ((float4*)B)[i] = v;
}

// ---------------- BN + residual + ReLU ----------------
__global__ __launch_bounds__(256) void final_kernel(
    const float* __restrict__ Cbuf, const float* __restrict__ stats,
    const float* __restrict__ g, const float* __restrict__ b,
    const float* __restrict__ xres, float* __restrict__ out) {
  int i = blockIdx.x * 256 + threadIdx.x;
  int c = (i >> 8) & 63;
  float mu  = stats[c] * (1.0f / NPIX);
  float var = fmaf(-mu, mu, stats[64 + c] * (1.0f / NPIX));
  float rs  = rsqrtf(var + 1e-5f);
  float ga  = g[c] * rs;
  float be  = fmaf(-mu, ga, b[c]);
  float4 v = ((const float4*)Cbuf)[i];
  float4 xr = ((const float4*)xres)[i];
  v.x = fmaxf(fmaf(v.x, ga, be) + xr.x, 0.0f);
  v.y = fmaxf(fmaf(v.y, ga, be) + xr.y, 0.0f);
  v.z = fmaxf(fmaf(v.z, ga, be) + xr.z, 0.0f);
  v.w = fmaxf(fmaf(v.w, ga, be) + xr.w, 0.0f);
  ((float4*)out)[i] = v;
}

extern "C" void kernel_launch(void* const* d_in, const int* in_sizes, int n_in,
                              void* d_out, int out_size, void* d_ws, size_t ws_size,
                              hipStream_t stream) {
  const float* x  = (const float*)d_in[0];
  const float* w1 = (const float*)d_in[1];
  const float* g1 = (const float*)d_in[2];
  const float* b1 = (const float*)d_in[3];
  const float* w2 = (const float*)d_in[4];
  const float* g2 = (const float*)d_in[5];
  const float* b2 = (const float*)d_in[6];
  float* outp = (float*)d_out;

  float* ws = (float*)d_ws;
  const size_t NEL = 2097152;          // 32*64*32*32
  float* bufA  = ws;                   // adder1 out, reused as adder2 out
  float* bufB  = ws + NEL;             // bn1relu out
  float* wt1   = ws + 2 * NEL;         // 36864
  float* wt2   = wt1 + CH * KDIM;      // 36864
  float* stats = wt2 + CH * KDIM;      // 256 floats: [s1,sq1,s2,sq2] x 64

  // 1. prep: transpose weights, zero stats
  prep_kernel<<<144, 256, 0, stream>>>(w1, w2, wt1, wt2, stats);

  dim3 agrid(8, 2, 32);
  // 2. adder1: x -> bufA, stats1 @ stats+0
  adder_kernel<<<agrid, 256, 0, stream>>>(x, wt1, bufA, stats);
  // 3. bn1 + relu: bufA -> bufB
  bnrelu_kernel<<<2048, 256, 0, stream>>>(bufA, stats, g1, b1, bufB);
  // 4. adder2: bufB -> bufA (reuse), stats2 @ stats+128
  adder_kernel<<<agrid, 256, 0, stream>>>(bufB, wt2, bufA, stats + 128);
  // 5. bn2 + residual + relu -> out
  final_kernel<<<2048, 256, 0, stream>>>(bufA, stats + 128, g2, b2, x, outp);
}

// Round 2
// 378.652 us; speedup vs baseline: 1.2891x; 1.2891x over previous
//
#include <hip/hip_runtime.h>

#define CH    64
#define HW    32
#define HWHW  1024      // 32*32
#define CHW   65536     // 64*1024
#define NPIX  32768.0f  // N*H*W per channel
#define KDIM  576       // 64*3*3

// ---------------- prep: transpose weights [co][k] -> [k][co], zero stats ----
__global__ __launch_bounds__(256) void prep_kernel(
    const float* __restrict__ w1, const float* __restrict__ w2,
    float* __restrict__ wt1, float* __restrict__ wt2,
    float* __restrict__ stats) {
  int i = blockIdx.x * 256 + threadIdx.x;
  if (i < 256) stats[i] = 0.0f;
  if (i < CH * KDIM) {
    int co = i / KDIM, k = i % KDIM;
    wt1[k * CH + co] = w1[i];
    wt2[k * CH + co] = w2[i];
  }
}

// ---------------- adder2d + fused per-channel stats ----------------
// grid (16 cog, 2 ht, 32 n), block 256 -> 1024 blocks = 4 blocks/CU.
// Each thread: 4 output channels x 2 pixels. Ping-pong prefetch of
// x (LDS) and w (SMEM) one iteration ahead to hide lgkmcnt drains.
__global__ __launch_bounds__(256, 4) void adder_kernel(
    const float* __restrict__ xin,   // [32][64][32][32]
    const float* __restrict__ wt,    // [576][64] transposed weights
    float* __restrict__ out,         // [32][64][32][32]
    float* __restrict__ stats) {     // [0..63]=sum, [64..127]=sumsq
  const int cog = blockIdx.x;        // 0..15
  const int ht  = blockIdx.y;        // 0..1
  const int n   = blockIdx.z;        // 0..31
  const int tid = threadIdx.x;
  const int co0 = cog * 4;
  const int h0  = ht * 16;
  const int r   = tid >> 4;          // 0..15 (row in tile)
  const int c0  = (tid & 15) * 2;    // 0..30 (col pair)

  // x tile: 8 ci-planes, 18 rows, width 37 (odd -> <=2-way conflicts = free)
  __shared__ float xs[8][18][37];
  {
    float* xsf = &xs[0][0][0];
    for (int i = tid; i < 8 * 18 * 37; i += 256) xsf[i] = 0.0f;
  }

  float acc[4][2];
#pragma unroll
  for (int co = 0; co < 4; ++co) { acc[co][0] = 0.0f; acc[co][1] = 0.0f; }

  const float* xb = xin + n * CHW;

  float xA[4], xB[4], wA[12], wB[12];

  // prime W pipeline for (cc=0, ci=0, kh=0)
  {
    const float* wp = wt + co0;
#pragma unroll
    for (int kw = 0; kw < 3; ++kw)
#pragma unroll
      for (int co = 0; co < 4; ++co) wA[kw * 4 + co] = wp[kw * CH + co];
  }

  for (int cc = 0; cc < CH; cc += 8) {
    __syncthreads();  // zero-fill done (cc=0) / previous compute done (cc>0)
    // stage x[n][cc+ci][h0-1+row][0..31] -> xs[ci][row][1+col]
    for (int idx = tid; idx < 1152; idx += 256) {
      int ci  = idx / 144;           // 18*8
      int rem = idx - ci * 144;
      int row = rem >> 3;
      int c4  = rem & 7;
      int hr  = h0 - 1 + row;
      if (hr >= 0 && hr < HW) {
        const float4 v = *(const float4*)(xb + (cc + ci) * HWHW + hr * HW + c4 * 4);
        xs[ci][row][1 + c4 * 4 + 0] = v.x;
        xs[ci][row][1 + c4 * 4 + 1] = v.y;
        xs[ci][row][1 + c4 * 4 + 2] = v.z;
        xs[ci][row][1 + c4 * 4 + 3] = v.w;
      }
    }
    __syncthreads();

    // prime X pipeline for it=0 (ci=0, kh=0)
#pragma unroll
    for (int j = 0; j < 4; ++j) xA[j] = xs[0][r][c0 + j];

#pragma unroll
    for (int s = 0; s < 12; ++s) {
      const int it1 = 2 * s + 1, it2 = 2 * s + 2;
      // prefetch it1 -> B
      {
        const int ci = it1 / 3, kh = it1 % 3;
#pragma unroll
        for (int j = 0; j < 4; ++j) xB[j] = xs[ci][r + kh][c0 + j];
        const float* wp = wt + (((cc + ci) * 3 + kh) * 3) * CH + co0;
#pragma unroll
        for (int kw = 0; kw < 3; ++kw)
#pragma unroll
          for (int co = 0; co < 4; ++co) wB[kw * 4 + co] = wp[kw * CH + co];
      }
      // compute it0 with A
#pragma unroll
      for (int kw = 0; kw < 3; ++kw)
#pragma unroll
        for (int co = 0; co < 4; ++co) {
          float w = wA[kw * 4 + co];
          acc[co][0] += __builtin_fabsf(xA[kw + 0] - w);
          acc[co][1] += __builtin_fabsf(xA[kw + 1] - w);
        }
      // prefetch it2 -> A (or first weights of next chunk)
      if (it2 < 24) {
        const int ci = it2 / 3, kh = it2 % 3;
#pragma unroll
        for (int j = 0; j < 4; ++j) xA[j] = xs[ci][r + kh][c0 + j];
        const float* wp = wt + (((cc + ci) * 3 + kh) * 3) * CH + co0;
#pragma unroll
        for (int kw = 0; kw < 3; ++kw)
#pragma unroll
          for (int co = 0; co < 4; ++co) wA[kw * 4 + co] = wp[kw * CH + co];
      } else {
        const int ncc = (cc + 8 < CH) ? cc + 8 : 0;  // dummy reload on last chunk
        const float* wp = wt + (ncc * 3) * 3 * CH + co0;
#pragma unroll
        for (int kw = 0; kw < 3; ++kw)
#pragma unroll
          for (int co = 0; co < 4; ++co) wA[kw * 4 + co] = wp[kw * CH + co];
      }
      // compute it1 with B
#pragma unroll
      for (int kw = 0; kw < 3; ++kw)
#pragma unroll
        for (int co = 0; co < 4; ++co) {
          float w = wB[kw * 4 + co];
          acc[co][0] += __builtin_fabsf(xB[kw + 0] - w);
          acc[co][1] += __builtin_fabsf(xB[kw + 1] - w);
        }
    }
  }

  // epilogue: write outputs (negated), wave-reduce per-channel stats, atomics
  const int lane  = tid & 63;
  const int obase = n * CHW + (h0 + r) * HW + c0;
#pragma unroll
  for (int co = 0; co < 4; ++co) {
    float v0 = -acc[co][0], v1 = -acc[co][1];
    *(float2*)(out + obase + (co0 + co) * HWHW) = make_float2(v0, v1);
    float sm = v0 + v1;
    float sq = v0 * v0 + v1 * v1;
#pragma unroll
    for (int m = 1; m < 64; m <<= 1) {
      sm += __shfl_xor(sm, m);
      sq += __shfl_xor(sq, m);
    }
    if (lane == 0) {
      atomicAdd(stats + (co0 + co), sm);
      atomicAdd(stats + 64 + (co0 + co), sq);
    }
  }
}

// ---------------- BN (train-mode, stats given) + ReLU ----------------
__global__ __launch_bounds__(256) void bnrelu_kernel(
    const float* __restrict__ A, const float* __restrict__ stats,
    const float* __restrict__ g, const float* __restrict__ b,
    float* __restrict__ B) {
  int i = blockIdx.x * 256 + threadIdx.x;  // float4 index, 524288 total
  int c = (i >> 8) & 63;
  float mu  = stats[c] * (1.0f / NPIX);
  float var = fmaf(-mu, mu, stats[64 + c] * (1.0f / NPIX));
  float rs  = rsqrtf(var + 1e-5f);
  float ga  = g[c] * rs;
  float be  = fmaf(-mu, ga, b[c]);
  float4 v = ((const float4*)A)[i];
  v.x = fmaxf(fmaf(v.x, ga, be), 0.0f);
  v.y = fmaxf(fmaf(v.y, ga, be), 0.0f);
  v.z = fmaxf(fmaf(v.z, ga, be), 0.0f);
  v.w = fmaxf(fmaf(v.w, ga, be), 0.0f);
  ((float4*)B)[i] = v;
}

// ---------------- BN + residual + ReLU ----------------
__global__ __launch_bounds__(256) void final_kernel(
    const float* __restrict__ Cbuf, const float* __restrict__ stats,
    const float* __restrict__ g, const float* __restrict__ b,
    const float* __restrict__ xres, float* __restrict__ out) {
  int i = blockIdx.x * 256 + threadIdx.x;
  int c = (i >> 8) & 63;
  float mu  = stats[c] * (1.0f / NPIX);
  float var = fmaf(-mu, mu, stats[64 + c] * (1.0f / NPIX));
  float rs  = rsqrtf(var + 1e-5f);
  float ga  = g[c] * rs;
  float be  = fmaf(-mu, ga, b[c]);
  float4 v = ((const float4*)Cbuf)[i];
  float4 xr = ((const float4*)xres)[i];
  v.x = fmaxf(fmaf(v.x, ga, be) + xr.x, 0.0f);
  v.y = fmaxf(fmaf(v.y, ga, be) + xr.y, 0.0f);
  v.z = fmaxf(fmaf(v.z, ga, be) + xr.z, 0.0f);
  v.w = fmaxf(fmaf(v.w, ga, be) + xr.w, 0.0f);
  ((float4*)out)[i] = v;
}

extern "C" void kernel_launch(void* const* d_in, const int* in_sizes, int n_in,
                              void* d_out, int out_size, void* d_ws, size_t ws_size,
                              hipStream_t stream) {
  const float* x  = (const float*)d_in[0];
  const float* w1 = (const float*)d_in[1];
  const float* g1 = (const float*)d_in[2];
  const float* b1 = (const float*)d_in[3];
  const float* w2 = (const float*)d_in[4];
  const float* g2 = (const float*)d_in[5];
  const float* b2 = (const float*)d_in[6];
  float* outp = (float*)d_out;

  float* ws = (float*)d_ws;
  const size_t NEL = 2097152;          // 32*64*32*32
  float* bufA  = ws;                   // adder1 out, reused as adder2 out
  float* bufB  = ws + NEL;             // bn1relu out
  float* wt1   = ws + 2 * NEL;         // 36864
  float* wt2   = wt1 + CH * KDIM;      // 36864
  float* stats = wt2 + CH * KDIM;      // 256 floats: [s1,sq1,s2,sq2] x 64

  // 1. prep: transpose weights, zero stats
  prep_kernel<<<144, 256, 0, stream>>>(w1, w2, wt1, wt2, stats);

  dim3 agrid(16, 2, 32);
  // 2. adder1: x -> bufA, stats1 @ stats+0
  adder_kernel<<<agrid, 256, 0, stream>>>(x, wt1, bufA, stats);
  // 3. bn1 + relu: bufA -> bufB
  bnrelu_kernel<<<2048, 256, 0, stream>>>(bufA, stats, g1, b1, bufB);
  // 4. adder2: bufB -> bufA (reuse), stats2 @ stats+128
  adder_kernel<<<agrid, 256, 0, stream>>>(bufB, wt2, bufA, stats + 128);
  // 5. bn2 + residual + relu -> out
  final_kernel<<<2048, 256, 0, stream>>>(bufA, stats + 128, g2, b2, x, outp);
}

// Round 3
// 356.840 us; speedup vs baseline: 1.3679x; 1.0611x over previous
//
#include <hip/hip_runtime.h>

#define CH    64
#define HWHW  1024      // 32*32
#define CHW   65536     // 64*1024
#define NPIX  32768.0f  // N*H*W per channel
#define KDIM  576       // 64*3*3

// ---------------- prep: transpose weights [co][k] -> [k][co], zero stats ----
__global__ __launch_bounds__(256) void prep_kernel(
    const float* __restrict__ w1, const float* __restrict__ w2,
    float* __restrict__ wt1, float* __restrict__ wt2,
    float* __restrict__ stats) {
  int i = blockIdx.x * 256 + threadIdx.x;
  if (i < 256) stats[i] = 0.0f;
  if (i < CH * KDIM) {
    int co = i / KDIM, k = i % KDIM;
    wt1[k * CH + co] = w1[i];
    wt2[k * CH + co] = w2[i];
  }
}

// ---------------- adder2d + fused per-channel stats ----------------
// grid (16 cog, 4 rg, 32 n) = 2048 blocks, block 256 (4 waves) -> 8 blocks/CU.
// Intra-block K-split: wave wv sums ci in [16*wv, 16*wv+16); cross-wave LDS
// reduce at the end. Each thread: 4 co x 4 px (1 row x 4 cols).
__global__ __launch_bounds__(256, 8) void adder_kernel(
    const float* __restrict__ xin,   // [32][64][32][32]
    const float* __restrict__ wt,    // [576][64] transposed weights
    float* __restrict__ out,         // [32][64][32][32]
    float* __restrict__ stats) {     // [0..63]=sum, [64..127]=sumsq
  const int cog  = blockIdx.x;       // 0..15
  const int rg   = blockIdx.y;       // 0..3 (8-row groups)
  const int n    = blockIdx.z;       // 0..31
  const int tid  = threadIdx.x;
  const int lane = tid & 63;
  const int wv   = __builtin_amdgcn_readfirstlane(tid >> 6);  // wave id 0..3
  const int co0  = cog * 4;
  const int r0   = lane >> 3;        // 0..7 row within group
  const int c0   = (lane & 7) * 4;   // 0,4,..,28

  // x tiles: [buf][wave-plane][10 rows][37] (width 37 odd -> 2-way = free)
  __shared__ float xs[2][4][10][37];
  __shared__ float red[64][17];      // cross-wave reduce scratch (+1 pad)
  const int XSHALF = 4 * 10 * 37;

  // ---- staging descriptors: items idx = tid (and tid+256 if tid<64) ----
  // item: ws = idx/80, row = (idx%80)>>3, c4 = idx&7; 80 = 10 rows * 8 f4
  const int i0 = tid,       ws0 = i0 / 80, rem0 = i0 % 80;
  const int row0 = rem0 >> 3, c40 = rem0 & 7;
  const int hr0 = rg * 8 - 1 + row0;
  const int i1 = tid + 256, ws1 = i1 / 80, rem1 = i1 % 80;
  const int row1 = rem1 >> 3, c41 = rem1 & 7;
  const int hr1 = rg * 8 - 1 + row1;
  const bool val0 = (hr0 >= 0) && (hr0 < 32);
  const bool val1 = (tid < 64) && (hr1 >= 0) && (hr1 < 32);
  const float* g0 = xin + n * CHW + ws0 * 16 * HWHW + hr0 * 32 + c40 * 4;
  const float* g1 = xin + n * CHW + ws1 * 16 * HWHW + hr1 * 32 + c41 * 4;
  float* l0 = &xs[0][ws0][row0][1 + c40 * 4];
  float* l1 = &xs[0][ws1][row1][1 + c41 * 4];

  // ---- prologue: load ci=0 planes, zero LDS, write, sync ----
  float4 a0, a1;
  if (val0) a0 = *(const float4*)g0;
  if (val1) a1 = *(const float4*)g1;
  {
    float* p = (float*)xs;
    for (int i = tid; i < 2 * XSHALF; i += 256) p[i] = 0.0f;
  }
  __syncthreads();
  if (val0) { l0[0] = a0.x; l0[1] = a0.y; l0[2] = a0.z; l0[3] = a0.w; }
  if (val1) { l1[0] = a1.x; l1[1] = a1.y; l1[2] = a1.z; l1[3] = a1.w; }
  __syncthreads();

  // ---- weights: wave-uniform -> scalar loads. phase p = ci_local*3 + kh ----
  const float* wtb = wt + (wv * 144) * 64 + co0;   // + p*192
  float wA[12], wB[12];
  auto LOADW = [&](float* dst, int p) {
    const float* wp = wtb + p * 192;
#pragma unroll
    for (int kw = 0; kw < 3; ++kw)
#pragma unroll
      for (int co = 0; co < 4; ++co) dst[kw * 4 + co] = wp[kw * 64 + co];
  };

  float acc[4][4];
#pragma unroll
  for (int co = 0; co < 4; ++co)
#pragma unroll
    for (int j = 0; j < 4; ++j) acc[co][j] = 0.0f;

  auto COMPUTE = [&](const float* w, int bufsel, int kh) {
    float xv[6];
#pragma unroll
    for (int j = 0; j < 6; ++j) xv[j] = xs[bufsel][wv][r0 + kh][c0 + j];
#pragma unroll
    for (int kw = 0; kw < 3; ++kw)
#pragma unroll
      for (int co = 0; co < 4; ++co) {
        float ww = w[kw * 4 + co];
        acc[co][0] += __builtin_fabsf(xv[kw + 0] - ww);
        acc[co][1] += __builtin_fabsf(xv[kw + 1] - ww);
        acc[co][2] += __builtin_fabsf(xv[kw + 2] - ww);
        acc[co][3] += __builtin_fabsf(xv[kw + 3] - ww);
      }
  };

  LOADW(wA, 0);
  for (int ci = 0; ci < 16; ci += 2) {
    const int p = ci * 3;
    // prefetch planes ci+1 into regs (ci+1 <= 15 always)
    float4 b0, b1;
    if (val0) b0 = *(const float4*)(g0 + (ci + 1) * HWHW);
    if (val1) b1 = *(const float4*)(g1 + (ci + 1) * HWHW);
    LOADW(wB, p + 1);
    COMPUTE(wA, 0, 0);
    LOADW(wA, p + 2);
    COMPUTE(wB, 0, 1);
    LOADW(wB, p + 3);
    COMPUTE(wA, 0, 2);
    if (val0) { float* d = l0 + XSHALF; d[0] = b0.x; d[1] = b0.y; d[2] = b0.z; d[3] = b0.w; }
    if (val1) { float* d = l1 + XSHALF; d[0] = b1.x; d[1] = b1.y; d[2] = b1.z; d[3] = b1.w; }
    __syncthreads();
    // prefetch planes ci+2 (guarded)
    const bool more = (ci + 2) < 16;
    float4 e0, e1;
    if (more && val0) e0 = *(const float4*)(g0 + (ci + 2) * HWHW);
    if (more && val1) e1 = *(const float4*)(g1 + (ci + 2) * HWHW);
    LOADW(wA, p + 4);
    COMPUTE(wB, 1, 0);
    LOADW(wB, p + 5);
    COMPUTE(wA, 1, 1);
    { int pn = more ? p + 6 : 0; LOADW(wA, pn); }
    COMPUTE(wB, 1, 2);
    if (more && val0) { l0[0] = e0.x; l0[1] = e0.y; l0[2] = e0.z; l0[3] = e0.w; }
    if (more && val1) { l1[0] = e1.x; l1[1] = e1.y; l1[2] = e1.z; l1[3] = e1.w; }
    __syncthreads();
  }

  // ---- cross-wave reduction: waves 1..3 add into wave0's acc ----
  float* af = &acc[0][0];
  for (int src = 1; src < 4; ++src) {
    if (wv == src) {
#pragma unroll
      for (int j = 0; j < 16; ++j) red[lane][j] = af[j];
    }
    __syncthreads();
    if (wv == 0) {
#pragma unroll
      for (int j = 0; j < 16; ++j) af[j] += red[lane][j];
    }
    __syncthreads();
  }

  // ---- wave0: negate, write out, fused stats ----
  if (wv == 0) {
    const int ob = n * CHW + (rg * 8 + r0) * 32 + c0;
#pragma unroll
    for (int co = 0; co < 4; ++co) {
      float t0 = -acc[co][0], t1 = -acc[co][1], t2 = -acc[co][2], t3 = -acc[co][3];
      *(float4*)(out + ob + (co0 + co) * HWHW) = make_float4(t0, t1, t2, t3);
      float sm = t0 + t1 + t2 + t3;
      float sq = t0 * t0 + t1 * t1 + t2 * t2 + t3 * t3;
#pragma unroll
      for (int m = 1; m < 64; m <<= 1) {
        sm += __shfl_xor(sm, m);
        sq += __shfl_xor(sq, m);
      }
      if (lane == 0) {
        atomicAdd(stats + co0 + co, sm);
        atomicAdd(stats + 64 + co0 + co, sq);
      }
    }
  }
}

// ---------------- BN (train-mode, stats given) + ReLU ----------------
__global__ __launch_bounds__(256) void bnrelu_kernel(
    const float* __restrict__ A, const float* __restrict__ stats,
    const float* __restrict__ g, const float* __restrict__ b,
    float* __restrict__ B) {
  int i = blockIdx.x * 256 + threadIdx.x;  // float4 index, 524288 total
  int c = (i >> 8) & 63;
  float mu  = stats[c] * (1.0f / NPIX);
  float var = fmaf(-mu, mu, stats[64 + c] * (1.0f / NPIX));
  float rs  = rsqrtf(var + 1e-5f);
  float ga  = g[c] * rs;
  float be  = fmaf(-mu, ga, b[c]);
  float4 v = ((const float4*)A)[i];
  v.x = fmaxf(fmaf(v.x, ga, be), 0.0f);
  v.y = fmaxf(fmaf(v.y, ga, be), 0.0f);
  v.z = fmaxf(fmaf(v.z, ga, be), 0.0f);
  v.w = fmaxf(fmaf(v.w, ga, be), 0.0f);
  ((float4*)B)[i] = v;
}

// ---------------- BN + residual + ReLU ----------------
__global__ __launch_bounds__(256) void final_kernel(
    const float* __restrict__ Cbuf, const float* __restrict__ stats,
    const float* __restrict__ g, const float* __restrict__ b,
    const float* __restrict__ xres, float* __restrict__ out) {
  int i = blockIdx.x * 256 + threadIdx.x;
  int c = (i >> 8) & 63;
  float mu  = stats[c] * (1.0f / NPIX);
  float var = fmaf(-mu, mu, stats[64 + c] * (1.0f / NPIX));
  float rs  = rsqrtf(var + 1e-5f);
  float ga  = g[c] * rs;
  float be  = fmaf(-mu, ga, b[c]);
  float4 v = ((const float4*)Cbuf)[i];
  float4 xr = ((const float4*)xres)[i];
  v.x = fmaxf(fmaf(v.x, ga, be) + xr.x, 0.0f);
  v.y = fmaxf(fmaf(v.y, ga, be) + xr.y, 0.0f);
  v.z = fmaxf(fmaf(v.z, ga, be) + xr.z, 0.0f);
  v.w = fmaxf(fmaf(v.w, ga, be) + xr.w, 0.0f);
  ((float4*)out)[i] = v;
}

extern "C" void kernel_launch(void* const* d_in, const int* in_sizes, int n_in,
                              void* d_out, int out_size, void* d_ws, size_t ws_size,
                              hipStream_t stream) {
  const float* x  = (const float*)d_in[0];
  const float* w1 = (const float*)d_in[1];
  const float* g1 = (const float*)d_in[2];
  const float* b1 = (const float*)d_in[3];
  const float* w2 = (const float*)d_in[4];
  const float* g2 = (const float*)d_in[5];
  const float* b2 = (const float*)d_in[6];
  float* outp = (float*)d_out;

  float* ws = (float*)d_ws;
  const size_t NEL = 2097152;          // 32*64*32*32
  float* bufA  = ws;                   // adder1 out, reused as adder2 out
  float* bufB  = ws + NEL;             // bn1relu out
  float* wt1   = ws + 2 * NEL;         // 36864
  float* wt2   = wt1 + CH * KDIM;      // 36864
  float* stats = wt2 + CH * KDIM;      // 256 floats: [s1,sq1,s2,sq2] x 64

  // 1. prep: transpose weights, zero stats
  prep_kernel<<<144, 256, 0, stream>>>(w1, w2, wt1, wt2, stats);

  dim3 agrid(16, 4, 32);
  // 2. adder1: x -> bufA, stats1 @ stats+0
  adder_kernel<<<agrid, 256, 0, stream>>>(x, wt1, bufA, stats);
  // 3. bn1 + relu: bufA -> bufB
  bnrelu_kernel<<<2048, 256, 0, stream>>>(bufA, stats, g1, b1, bufB);
  // 4. adder2: bufB -> bufA (reuse), stats2 @ stats+128
  adder_kernel<<<agrid, 256, 0, stream>>>(bufB, wt2, bufA, stats + 128);
  // 5. bn2 + residual + relu -> out
  final_kernel<<<2048, 256, 0, stream>>>(bufA, stats + 128, g2, b2, x, outp);
}

// Round 4
// 210.822 us; speedup vs baseline: 2.3154x; 1.6926x over previous
//
#include <hip/hip_runtime.h>

#define CH    64
#define HWHW  1024      // 32*32
#define CHW   65536     // 64*1024
#define NPIX  32768.0f  // N*H*W per channel
#define KDIM  576       // 64*3*3

// ---------------- prep: transpose weights [co][k] -> [k][co], zero stats ----
__global__ __launch_bounds__(256) void prep_kernel(
    const float* __restrict__ w1, const float* __restrict__ w2,
    float* __restrict__ wt1, float* __restrict__ wt2,
    float* __restrict__ stats) {
  int i = blockIdx.x * 256 + threadIdx.x;
  if (i < 256) stats[i] = 0.0f;
  if (i < CH * KDIM) {
    int co = i / KDIM, k = i % KDIM;
    wt1[k * CH + co] = w1[i];
    wt2[k * CH + co] = w2[i];
  }
}

// ---------------- adder2d + fused per-channel stats ----------------
// grid (16 cog, 4 rg, 32 n) = 2048 blocks, block 256 (4 waves).
// Intra-block K-split: wave wv sums ci in [16*wv, 16*wv+16); cross-wave LDS
// reduce at the end. Each thread: 4 co x 4 px (1 row x 4 cols).
// launch_bounds(256,4): VGPR cap 128 -> NO SPILL (R3's (256,8) forced 32 VGPRs
// and 700MB of scratch traffic).
__global__ __launch_bounds__(256, 4) void adder_kernel(
    const float* __restrict__ xin,   // [32][64][32][32]
    const float* __restrict__ wt,    // [576][64] transposed weights
    float* __restrict__ out,         // [32][64][32][32]
    float* __restrict__ stats) {     // [0..63]=sum, [64..127]=sumsq
  const int cog  = blockIdx.x;       // 0..15
  const int rg   = blockIdx.y;       // 0..3 (8-row groups)
  const int n    = blockIdx.z;       // 0..31
  const int tid  = threadIdx.x;
  const int lane = tid & 63;
  const int wv   = __builtin_amdgcn_readfirstlane(tid >> 6);  // wave id 0..3
  const int co0  = cog * 4;
  const int r0   = lane >> 3;        // 0..7 row within group
  const int c0   = (lane & 7) * 4;   // 0,4,..,28

  // x tiles: [buf][wave-plane][10 rows][37] (width 37 odd -> 2-way = free)
  __shared__ float xs[2][4][10][37];
  __shared__ float red[64][17];      // cross-wave reduce scratch (+1 pad)
  const int XSHALF = 4 * 10 * 37;

  // ---- staging descriptors: items idx = tid (and tid+256 if tid<64) ----
  // item: ws = idx/80, row = (idx%80)>>3, c4 = idx&7; 80 = 10 rows * 8 f4
  const int i0 = tid,       ws0 = i0 / 80, rem0 = i0 % 80;
  const int row0 = rem0 >> 3, c40 = rem0 & 7;
  const int hr0 = rg * 8 - 1 + row0;
  const int i1 = tid + 256, ws1 = i1 / 80, rem1 = i1 % 80;
  const int row1 = rem1 >> 3, c41 = rem1 & 7;
  const int hr1 = rg * 8 - 1 + row1;
  const bool val0 = (hr0 >= 0) && (hr0 < 32);
  const bool val1 = (tid < 64) && (hr1 >= 0) && (hr1 < 32);
  const float* g0 = xin + n * CHW + ws0 * 16 * HWHW + hr0 * 32 + c40 * 4;
  const float* g1 = xin + n * CHW + ws1 * 16 * HWHW + hr1 * 32 + c41 * 4;
  float* l0 = &xs[0][ws0][row0][1 + c40 * 4];
  float* l1 = &xs[0][ws1][row1][1 + c41 * 4];

  // ---- prologue: load ci=0 planes, zero LDS, write, sync ----
  float4 a0, a1;
  if (val0) a0 = *(const float4*)g0;
  if (val1) a1 = *(const float4*)g1;
  {
    float* p = (float*)xs;
    for (int i = tid; i < 2 * XSHALF; i += 256) p[i] = 0.0f;
  }
  __syncthreads();
  if (val0) { l0[0] = a0.x; l0[1] = a0.y; l0[2] = a0.z; l0[3] = a0.w; }
  if (val1) { l1[0] = a1.x; l1[1] = a1.y; l1[2] = a1.z; l1[3] = a1.w; }
  __syncthreads();

  // ---- weights: wave-uniform -> scalar loads. phase p = ci_local*3 + kh ----
  const float* wtb = wt + (wv * 144) * 64 + co0;   // + p*192
  float wA[12], wB[12];
  auto LOADW = [&](float* dst, int p) {
    const float* wp = wtb + p * 192;
#pragma unroll
    for (int kw = 0; kw < 3; ++kw)
#pragma unroll
      for (int co = 0; co < 4; ++co) dst[kw * 4 + co] = wp[kw * 64 + co];
  };

  float acc[4][4];
#pragma unroll
  for (int co = 0; co < 4; ++co)
#pragma unroll
    for (int j = 0; j < 4; ++j) acc[co][j] = 0.0f;

  auto COMPUTE = [&](const float* w, int bufsel, int kh) {
    float xv[6];
#pragma unroll
    for (int j = 0; j < 6; ++j) xv[j] = xs[bufsel][wv][r0 + kh][c0 + j];
#pragma unroll
    for (int kw = 0; kw < 3; ++kw)
#pragma unroll
      for (int co = 0; co < 4; ++co) {
        float ww = w[kw * 4 + co];
        acc[co][0] += __builtin_fabsf(xv[kw + 0] - ww);
        acc[co][1] += __builtin_fabsf(xv[kw + 1] - ww);
        acc[co][2] += __builtin_fabsf(xv[kw + 2] - ww);
        acc[co][3] += __builtin_fabsf(xv[kw + 3] - ww);
      }
  };

  LOADW(wA, 0);
  for (int ci = 0; ci < 16; ci += 2) {
    const int p = ci * 3;
    // prefetch planes ci+1 into regs (ci+1 <= 15 always)
    float4 b0, b1;
    if (val0) b0 = *(const float4*)(g0 + (ci + 1) * HWHW);
    if (val1) b1 = *(const float4*)(g1 + (ci + 1) * HWHW);
    LOADW(wB, p + 1);
    COMPUTE(wA, 0, 0);
    LOADW(wA, p + 2);
    COMPUTE(wB, 0, 1);
    LOADW(wB, p + 3);
    COMPUTE(wA, 0, 2);
    if (val0) { float* d = l0 + XSHALF; d[0] = b0.x; d[1] = b0.y; d[2] = b0.z; d[3] = b0.w; }
    if (val1) { float* d = l1 + XSHALF; d[0] = b1.x; d[1] = b1.y; d[2] = b1.z; d[3] = b1.w; }
    __syncthreads();
    // prefetch planes ci+2 (guarded)
    const bool more = (ci + 2) < 16;
    float4 e0, e1;
    if (more && val0) e0 = *(const float4*)(g0 + (ci + 2) * HWHW);
    if (more && val1) e1 = *(const float4*)(g1 + (ci + 2) * HWHW);
    LOADW(wA, p + 4);
    COMPUTE(wB, 1, 0);
    LOADW(wB, p + 5);
    COMPUTE(wA, 1, 1);
    { int pn = more ? p + 6 : 0; LOADW(wA, pn); }
    COMPUTE(wB, 1, 2);
    if (more && val0) { l0[0] = e0.x; l0[1] = e0.y; l0[2] = e0.z; l0[3] = e0.w; }
    if (more && val1) { l1[0] = e1.x; l1[1] = e1.y; l1[2] = e1.z; l1[3] = e1.w; }
    __syncthreads();
  }

  // ---- cross-wave reduction: waves 1..3 add into wave0's acc ----
  float* af = &acc[0][0];
  for (int src = 1; src < 4; ++src) {
    if (wv == src) {
#pragma unroll
      for (int j = 0; j < 16; ++j) red[lane][j] = af[j];
    }
    __syncthreads();
    if (wv == 0) {
#pragma unroll
      for (int j = 0; j < 16; ++j) af[j] += red[lane][j];
    }
    __syncthreads();
  }

  // ---- wave0: negate, write out, fused stats ----
  if (wv == 0) {
    const int ob = n * CHW + (rg * 8 + r0) * 32 + c0;
#pragma unroll
    for (int co = 0; co < 4; ++co) {
      float t0 = -acc[co][0], t1 = -acc[co][1], t2 = -acc[co][2], t3 = -acc[co][3];
      *(float4*)(out + ob + (co0 + co) * HWHW) = make_float4(t0, t1, t2, t3);
      float sm = t0 + t1 + t2 + t3;
      float sq = t0 * t0 + t1 * t1 + t2 * t2 + t3 * t3;
#pragma unroll
      for (int m = 1; m < 64; m <<= 1) {
        sm += __shfl_xor(sm, m);
        sq += __shfl_xor(sq, m);
      }
      if (lane == 0) {
        atomicAdd(stats + co0 + co, sm);
        atomicAdd(stats + 64 + co0 + co, sq);
      }
    }
  }
}

// ---------------- BN (train-mode, stats given) + ReLU ----------------
__global__ __launch_bounds__(256) void bnrelu_kernel(
    const float* __restrict__ A, const float* __restrict__ stats,
    const float* __restrict__ g, const float* __restrict__ b,
    float* __restrict__ B) {
  int i = blockIdx.x * 256 + threadIdx.x;  // float4 index, 524288 total
  int c = (i >> 8) & 63;
  float mu  = stats[c] * (1.0f / NPIX);
  float var = fmaf(-mu, mu, stats[64 + c] * (1.0f / NPIX));
  float rs  = rsqrtf(var + 1e-5f);
  float ga  = g[c] * rs;
  float be  = fmaf(-mu, ga, b[c]);
  float4 v = ((const float4*)A)[i];
  v.x = fmaxf(fmaf(v.x, ga, be), 0.0f);
  v.y = fmaxf(fmaf(v.y, ga, be), 0.0f);
  v.z = fmaxf(fmaf(v.z, ga, be), 0.0f);
  v.w = fmaxf(fmaf(v.w, ga, be), 0.0f);
  ((float4*)B)[i] = v;
}

// ---------------- BN + residual + ReLU ----------------
__global__ __launch_bounds__(256) void final_kernel(
    const float* __restrict__ Cbuf, const float* __restrict__ stats,
    const float* __restrict__ g, const float* __restrict__ b,
    const float* __restrict__ xres, float* __restrict__ out) {
  int i = blockIdx.x * 256 + threadIdx.x;
  int c = (i >> 8) & 63;
  float mu  = stats[c] * (1.0f / NPIX);
  float var = fmaf(-mu, mu, stats[64 + c] * (1.0f / NPIX));
  float rs  = rsqrtf(var + 1e-5f);
  float ga  = g[c] * rs;
  float be  = fmaf(-mu, ga, b[c]);
  float4 v = ((const float4*)Cbuf)[i];
  float4 xr = ((const float4*)xres)[i];
  v.x = fmaxf(fmaf(v.x, ga, be) + xr.x, 0.0f);
  v.y = fmaxf(fmaf(v.y, ga, be) + xr.y, 0.0f);
  v.z = fmaxf(fmaf(v.z, ga, be) + xr.z, 0.0f);
  v.w = fmaxf(fmaf(v.w, ga, be) + xr.w, 0.0f);
  ((float4*)out)[i] = v;
}

extern "C" void kernel_launch(void* const* d_in, const int* in_sizes, int n_in,
                              void* d_out, int out_size, void* d_ws, size_t ws_size,
                              hipStream_t stream) {
  const float* x  = (const float*)d_in[0];
  const float* w1 = (const float*)d_in[1];
  const float* g1 = (const float*)d_in[2];
  const float* b1 = (const float*)d_in[3];
  const float* w2 = (const float*)d_in[4];
  const float* g2 = (const float*)d_in[5];
  const float* b2 = (const float*)d_in[6];
  float* outp = (float*)d_out;

  float* ws = (float*)d_ws;
  const size_t NEL = 2097152;          // 32*64*32*32
  float* bufA  = ws;                   // adder1 out, reused as adder2 out
  float* bufB  = ws + NEL;             // bn1relu out
  float* wt1   = ws + 2 * NEL;         // 36864
  float* wt2   = wt1 + CH * KDIM;      // 36864
  float* stats = wt2 + CH * KDIM;      // 256 floats: [s1,sq1,s2,sq2] x 64

  // 1. prep: transpose weights, zero stats
  prep_kernel<<<144, 256, 0, stream>>>(w1, w2, wt1, wt2, stats);

  dim3 agrid(16, 4, 32);
  // 2. adder1: x -> bufA, stats1 @ stats+0
  adder_kernel<<<agrid, 256, 0, stream>>>(x, wt1, bufA, stats);
  // 3. bn1 + relu: bufA -> bufB
  bnrelu_kernel<<<2048, 256, 0, stream>>>(bufA, stats, g1, b1, bufB);
  // 4. adder2: bufB -> bufA (reuse), stats2 @ stats+128
  adder_kernel<<<agrid, 256, 0, stream>>>(bufB, wt2, bufA, stats + 128);
  // 5. bn2 + residual + relu -> out
  final_kernel<<<2048, 256, 0, stream>>>(bufA, stats + 128, g2, b2, x, outp);
}

// Round 5
// 171.816 us; speedup vs baseline: 2.8410x; 1.2270x over previous
//
#include <hip/hip_runtime.h>

#define CH    64
#define HWHW  1024      // 32*32
#define CHW   65536     // 64*1024
#define NPIX  32768.0f  // N*H*W per channel
#define KDIM  576       // 64*3*3

#define QSCALE 524288.0f          // 2^19
#define QBIAS  4194304.5f         // 8*2^19 + 0.5 (round-to-nearest)
#define Q0     4194304u           // quant(0.0f)
#define QINV   1.9073486328125e-6f // 2^-19

__device__ __forceinline__ unsigned quantf(float x) {
  return (unsigned)fmaf(x, QSCALE, QBIAS);  // v_fma + v_cvt_u32_f32
}

// acc += |x - w| in ONE full-rate VALU instruction
__device__ __forceinline__ unsigned sad_acc(unsigned x, unsigned w, unsigned a) {
  unsigned d;
  asm("v_sad_u32 %0, %1, %2, %3" : "=v"(d) : "v"(x), "s"(w), "v"(a));
  return d;
}

// ---------------- prep: quantize+transpose weights, zero stats ----
__global__ __launch_bounds__(256) void prep_kernel(
    const float* __restrict__ w1, const float* __restrict__ w2,
    unsigned* __restrict__ wt1, unsigned* __restrict__ wt2,
    float* __restrict__ stats) {
  int i = blockIdx.x * 256 + threadIdx.x;
  if (i < 256) stats[i] = 0.0f;
  if (i < CH * KDIM) {
    int co = i / KDIM, k = i % KDIM;
    wt1[k * CH + co] = quantf(w1[i]);
    wt2[k * CH + co] = quantf(w2[i]);
  }
}

// ---------------- adder2d + fused per-channel stats ----------------
// grid (16 cog, 4 rg, 32 n) = 2048 blocks, block 256 (4 waves).
// Wave wv sums ci in [16*wv, 16*wv+16); cross-wave LDS reduce at end.
// Each thread: 4 co x 4 px. Fixed-point x/w; term = one v_sad_u32.
__global__ __launch_bounds__(256, 4) void adder_kernel(
    const float* __restrict__ xin,    // [32][64][32][32] fp32
    const unsigned* __restrict__ wt,  // [576][64] quantized weights
    float* __restrict__ out,          // [32][64][32][32] fp32
    float* __restrict__ stats) {      // [0..63]=sum, [64..127]=sumsq
  const int cog  = blockIdx.x;       // 0..15
  const int rg   = blockIdx.y;       // 0..3 (8-row groups)
  const int n    = blockIdx.z;       // 0..31
  const int tid  = threadIdx.x;
  const int lane = tid & 63;
  const int wv   = __builtin_amdgcn_readfirstlane(tid >> 6);  // wave id 0..3
  const int co0  = cog * 4;
  const int r0   = lane >> 3;        // 0..7 row within group
  const int c0   = (lane & 7) * 4;   // 0,4,..,28

  // x tiles (quantized): [buf][wave-plane][10 rows][37]
  __shared__ unsigned xs[2][4][10][37];
  __shared__ unsigned red[64][17];   // cross-wave reduce scratch (+1 pad)
  const int XSHALF = 4 * 10 * 37;

  // ---- staging descriptors: items idx = tid (and tid+256 if tid<64) ----
  const int i0 = tid,       ws0 = i0 / 80, rem0 = i0 % 80;
  const int row0 = rem0 >> 3, c40 = rem0 & 7;
  const int hr0 = rg * 8 - 1 + row0;
  const int i1 = tid + 256, ws1 = i1 / 80, rem1 = i1 % 80;
  const int row1 = rem1 >> 3, c41 = rem1 & 7;
  const int hr1 = rg * 8 - 1 + row1;
  const bool val0 = (hr0 >= 0) && (hr0 < 32);
  const bool val1 = (tid < 64) && (hr1 >= 0) && (hr1 < 32);
  const float* g0 = xin + n * CHW + ws0 * 16 * HWHW + hr0 * 32 + c40 * 4;
  const float* g1 = xin + n * CHW + ws1 * 16 * HWHW + hr1 * 32 + c41 * 4;
  unsigned* l0 = &xs[0][ws0][row0][1 + c40 * 4];
  unsigned* l1 = &xs[0][ws1][row1][1 + c41 * 4];

  // ---- prologue: load ci=0 planes, fill LDS with Q(0) halo, write, sync ----
  float4 a0, a1;
  if (val0) a0 = *(const float4*)g0;
  if (val1) a1 = *(const float4*)g1;
  {
    unsigned* p = (unsigned*)xs;
    for (int i = tid; i < 2 * XSHALF; i += 256) p[i] = Q0;
  }
  __syncthreads();
  if (val0) { l0[0] = quantf(a0.x); l0[1] = quantf(a0.y); l0[2] = quantf(a0.z); l0[3] = quantf(a0.w); }
  if (val1) { l1[0] = quantf(a1.x); l1[1] = quantf(a1.y); l1[2] = quantf(a1.z); l1[3] = quantf(a1.w); }
  __syncthreads();

  // ---- weights: wave-uniform -> scalar loads. phase p = ci_local*3 + kh ----
  const unsigned* wtb = wt + (wv * 144) * 64 + co0;   // + p*192
  unsigned wA[12], wB[12];
  auto LOADW = [&](unsigned* dst, int p) {
    const unsigned* wp = wtb + p * 192;
#pragma unroll
    for (int kw = 0; kw < 3; ++kw)
#pragma unroll
      for (int co = 0; co < 4; ++co) dst[kw * 4 + co] = wp[kw * 64 + co];
  };

  unsigned acc[4][4];
#pragma unroll
  for (int co = 0; co < 4; ++co)
#pragma unroll
    for (int j = 0; j < 4; ++j) acc[co][j] = 0u;

  auto COMPUTE = [&](const unsigned* w, int bufsel, int kh) {
    unsigned xv[6];
#pragma unroll
    for (int j = 0; j < 6; ++j) xv[j] = xs[bufsel][wv][r0 + kh][c0 + j];
#pragma unroll
    for (int kw = 0; kw < 3; ++kw)
#pragma unroll
      for (int co = 0; co < 4; ++co) {
        unsigned ww = w[kw * 4 + co];
        acc[co][0] = sad_acc(xv[kw + 0], ww, acc[co][0]);
        acc[co][1] = sad_acc(xv[kw + 1], ww, acc[co][1]);
        acc[co][2] = sad_acc(xv[kw + 2], ww, acc[co][2]);
        acc[co][3] = sad_acc(xv[kw + 3], ww, acc[co][3]);
      }
  };

  LOADW(wA, 0);
  for (int ci = 0; ci < 16; ci += 2) {
    const int p = ci * 3;
    // prefetch planes ci+1 into regs (ci+1 <= 15 always)
    float4 b0, b1;
    if (val0) b0 = *(const float4*)(g0 + (ci + 1) * HWHW);
    if (val1) b1 = *(const float4*)(g1 + (ci + 1) * HWHW);
    LOADW(wB, p + 1);
    COMPUTE(wA, 0, 0);
    LOADW(wA, p + 2);
    COMPUTE(wB, 0, 1);
    LOADW(wB, p + 3);
    COMPUTE(wA, 0, 2);
    if (val0) { unsigned* d = l0 + XSHALF; d[0] = quantf(b0.x); d[1] = quantf(b0.y); d[2] = quantf(b0.z); d[3] = quantf(b0.w); }
    if (val1) { unsigned* d = l1 + XSHALF; d[0] = quantf(b1.x); d[1] = quantf(b1.y); d[2] = quantf(b1.z); d[3] = quantf(b1.w); }
    __syncthreads();
    // prefetch planes ci+2 (guarded)
    const bool more = (ci + 2) < 16;
    float4 e0, e1;
    if (more && val0) e0 = *(const float4*)(g0 + (ci + 2) * HWHW);
    if (more && val1) e1 = *(const float4*)(g1 + (ci + 2) * HWHW);
    LOADW(wA, p + 4);
    COMPUTE(wB, 1, 0);
    LOADW(wB, p + 5);
    COMPUTE(wA, 1, 1);
    { int pn = more ? p + 6 : 0; LOADW(wA, pn); }
    COMPUTE(wB, 1, 2);
    if (more && val0) { l0[0] = quantf(e0.x); l0[1] = quantf(e0.y); l0[2] = quantf(e0.z); l0[3] = quantf(e0.w); }
    if (more && val1) { l1[0] = quantf(e1.x); l1[1] = quantf(e1.y); l1[2] = quantf(e1.z); l1[3] = quantf(e1.w); }
    __syncthreads();
  }

  // ---- cross-wave reduction: waves 1..3 add into wave0's acc ----
  unsigned* af = &acc[0][0];
  for (int src = 1; src < 4; ++src) {
    if (wv == src) {
#pragma unroll
      for (int j = 0; j < 16; ++j) red[lane][j] = af[j];
    }
    __syncthreads();
    if (wv == 0) {
#pragma unroll
      for (int j = 0; j < 16; ++j) af[j] += red[lane][j];
    }
    __syncthreads();
  }

  // ---- wave0: convert, negate, write out, fused stats ----
  if (wv == 0) {
    const int ob = n * CHW + (rg * 8 + r0) * 32 + c0;
#pragma unroll
    for (int co = 0; co < 4; ++co) {
      float t0 = -(float)acc[co][0] * QINV;
      float t1 = -(float)acc[co][1] * QINV;
      float t2 = -(float)acc[co][2] * QINV;
      float t3 = -(float)acc[co][3] * QINV;
      *(float4*)(out + ob + (co0 + co) * HWHW) = make_float4(t0, t1, t2, t3);
      float sm = t0 + t1 + t2 + t3;
      float sq = t0 * t0 + t1 * t1 + t2 * t2 + t3 * t3;
#pragma unroll
      for (int m = 1; m < 64; m <<= 1) {
        sm += __shfl_xor(sm, m);
        sq += __shfl_xor(sq, m);
      }
      if (lane == 0) {
        atomicAdd(stats + co0 + co, sm);
        atomicAdd(stats + 64 + co0 + co, sq);
      }
    }
  }
}

// ---------------- BN (train-mode, stats given) + ReLU ----------------
__global__ __launch_bounds__(256) void bnrelu_kernel(
    const float* __restrict__ A, const float* __restrict__ stats,
    const float* __restrict__ g, const float* __restrict__ b,
    float* __restrict__ B) {
  int i = blockIdx.x * 256 + threadIdx.x;  // float4 index, 524288 total
  int c = (i >> 8) & 63;
  float mu  = stats[c] * (1.0f / NPIX);
  float var = fmaf(-mu, mu, stats[64 + c] * (1.0f / NPIX));
  float rs  = rsqrtf(var + 1e-5f);
  float ga  = g[c] * rs;
  float be  = fmaf(-mu, ga, b[c]);
  float4 v = ((const float4*)A)[i];
  v.x = fmaxf(fmaf(v.x, ga, be), 0.0f);
  v.y = fmaxf(fmaf(v.y, ga, be), 0.0f);
  v.z = fmaxf(fmaf(v.z, ga, be), 0.0f);
  v.w = fmaxf(fmaf(v.w, ga, be), 0.0f);
  ((float4*)B)[i] = v;
}

// ---------------- BN + residual + ReLU ----------------
__global__ __launch_bounds__(256) void final_kernel(
    const float* __restrict__ Cbuf, const float* __restrict__ stats,
    const float* __restrict__ g, const float* __restrict__ b,
    const float* __restrict__ xres, float* __restrict__ out) {
  int i = blockIdx.x * 256 + threadIdx.x;
  int c = (i >> 8) & 63;
  float mu  = stats[c] * (1.0f / NPIX);
  float var = fmaf(-mu, mu, stats[64 + c] * (1.0f / NPIX));
  float rs  = rsqrtf(var + 1e-5f);
  float ga  = g[c] * rs;
  float be  = fmaf(-mu, ga, b[c]);
  float4 v = ((const float4*)Cbuf)[i];
  float4 xr = ((const float4*)xres)[i];
  v.x = fmaxf(fmaf(v.x, ga, be) + xr.x, 0.0f);
  v.y = fmaxf(fmaf(v.y, ga, be) + xr.y, 0.0f);
  v.z = fmaxf(fmaf(v.z, ga, be) + xr.z, 0.0f);
  v.w = fmaxf(fmaf(v.w, ga, be) + xr.w, 0.0f);
  ((float4*)out)[i] = v;
}

extern "C" void kernel_launch(void* const* d_in, const int* in_sizes, int n_in,
                              void* d_out, int out_size, void* d_ws, size_t ws_size,
                              hipStream_t stream) {
  const float* x  = (const float*)d_in[0];
  const float* w1 = (const float*)d_in[1];
  const float* g1 = (const float*)d_in[2];
  const float* b1 = (const float*)d_in[3];
  const float* w2 = (const float*)d_in[4];
  const float* g2 = (const float*)d_in[5];
  const float* b2 = (const float*)d_in[6];
  float* outp = (float*)d_out;

  float* ws = (float*)d_ws;
  const size_t NEL = 2097152;          // 32*64*32*32
  float*    bufA  = ws;                // adder1 out, reused as adder2 out
  float*    bufB  = ws + NEL;          // bn1relu out
  unsigned* wt1   = (unsigned*)(ws + 2 * NEL);   // 36864
  unsigned* wt2   = wt1 + CH * KDIM;             // 36864
  float*    stats = (float*)(wt2 + CH * KDIM);   // 256 floats

  // 1. prep: quantize+transpose weights, zero stats
  prep_kernel<<<144, 256, 0, stream>>>(w1, w2, wt1, wt2, stats);

  dim3 agrid(16, 4, 32);
  // 2. adder1: x -> bufA, stats1 @ stats+0
  adder_kernel<<<agrid, 256, 0, stream>>>(x, wt1, bufA, stats);
  // 3. bn1 + relu: bufA -> bufB
  bnrelu_kernel<<<2048, 256, 0, stream>>>(bufA, stats, g1, b1, bufB);
  // 4. adder2: bufB -> bufA (reuse), stats2 @ stats+128
  adder_kernel<<<agrid, 256, 0, stream>>>(bufB, wt2, bufA, stats + 128);
  // 5. bn2 + residual + relu -> out
  final_kernel<<<2048, 256, 0, stream>>>(bufA, stats + 128, g2, b2, x, outp);
}

// Round 6
// 159.029 us; speedup vs baseline: 3.0695x; 1.0804x over previous
//
#include <hip/hip_runtime.h>

#define CH    64
#define HWHW  1024      // 32*32
#define CHW   65536     // 64*1024
#define NPIX  32768.0f  // N*H*W per channel
#define KDIM  576       // 64*3*3

#define QSCALE 524288.0f          // 2^19
#define QBIAS  4194304.5f         // 8*2^19 + 0.5 (round-to-nearest)
#define Q0     4194304u           // quant(0.0f)
#define QINV   1.9073486328125e-6f // 2^-19

__device__ __forceinline__ unsigned quantf(float x) {
  return (unsigned)fmaf(x, QSCALE, QBIAS);  // v_fma + v_cvt_u32_f32
}

// acc += |x - w| in ONE VALU instruction (all-VGPR VOP3)
__device__ __forceinline__ unsigned sad_acc(unsigned x, unsigned w, unsigned a) {
  unsigned d;
  asm("v_sad_u32 %0, %1, %2, %3" : "=v"(d) : "v"(x), "v"(w), "v"(a));
  return d;
}

// ---------------- prep: quantize weights into per-block LDS-friendly layout --
// dst layout: [cog 0..15][k 0..575][co_lo 0..3]  (2304 dwords per cog block)
__global__ __launch_bounds__(256) void prep_kernel(
    const float* __restrict__ w1, const float* __restrict__ w2,
    unsigned* __restrict__ wt1, unsigned* __restrict__ wt2,
    float* __restrict__ stats) {
  int i = blockIdx.x * 256 + threadIdx.x;
  if (i < 256) stats[i] = 0.0f;
  if (i < CH * KDIM) {
    int co = i / KDIM, k = i % KDIM;
    int dst = (co >> 2) * 2304 + k * 4 + (co & 3);
    wt1[dst] = quantf(w1[i]);
    wt2[dst] = quantf(w2[i]);
  }
}

// ---------------- adder2d + fused per-channel stats ----------------
// grid (16 cog, 4 rg, 32 n) = 2048 blocks, block 256 (4 waves).
// Wave wv sums ci in [16*wv, 16*wv+16); cross-wave LDS reduce at end.
// Each thread: 4 co x 4 px. ALL inner-loop operands via DS (in-order lgkm):
// weights staged to LDS in prologue, x rows 16B-aligned for b128+b64 reads.
__global__ __launch_bounds__(256, 4) void adder_kernel(
    const float* __restrict__ xin,    // [32][64][32][32] fp32
    const unsigned* __restrict__ wt,  // [16][576][4] quantized weights
    float* __restrict__ out,          // [32][64][32][32] fp32
    float* __restrict__ stats) {      // [0..63]=sum, [64..127]=sumsq
  const int cog  = blockIdx.x;       // 0..15
  const int rg   = blockIdx.y;       // 0..3 (8-row groups)
  const int n    = blockIdx.z;       // 0..31
  const int tid  = threadIdx.x;
  const int lane = tid & 63;
  const int wv   = __builtin_amdgcn_readfirstlane(tid >> 6);  // wave id 0..3
  const int co0  = cog * 4;
  const int r0   = lane >> 3;        // 0..7 row within group
  const int c0   = (lane & 7) * 4;   // 0,4,..,28

  // x tiles (quantized): [buf][wave-plane][10 rows][40] -- 16B-aligned rows,
  // data col c at index c+1; banks: r0 vs r0+4 alias -> 2-way = free
  __shared__ unsigned xs[2][4][10][40];   // 12800 B
  __shared__ unsigned wl[2304];           // 9216 B block's weight slice
  __shared__ unsigned red[64][17];        // 4352 B reduce scratch
  const int XSHALF = 4 * 10 * 40;

  // ---- staging descriptors: items idx = tid (and tid+256 if tid<64) ----
  const int i0 = tid,       ws0 = i0 / 80, rem0 = i0 % 80;
  const int row0 = rem0 >> 3, c40 = rem0 & 7;
  const int hr0 = rg * 8 - 1 + row0;
  const int i1 = tid + 256, ws1 = i1 / 80, rem1 = i1 % 80;
  const int row1 = rem1 >> 3, c41 = rem1 & 7;
  const int hr1 = rg * 8 - 1 + row1;
  const bool val0 = (hr0 >= 0) && (hr0 < 32);
  const bool val1 = (tid < 64) && (hr1 >= 0) && (hr1 < 32);
  const float* g0 = xin + n * CHW + ws0 * 16 * HWHW + hr0 * 32 + c40 * 4;
  const float* g1 = xin + n * CHW + ws1 * 16 * HWHW + hr1 * 32 + c41 * 4;
  unsigned* l0 = &xs[0][ws0][row0][1 + c40 * 4];
  unsigned* l1 = &xs[0][ws1][row1][1 + c41 * 4];

  // ---- prologue: stage weights->LDS, ci=0 x planes, Q0 halo fill ----
  {
    const uint4* wsrc = (const uint4*)(wt + cog * 2304);
    uint4* wdst = (uint4*)wl;
    for (int i = tid; i < 576; i += 256) wdst[i] = wsrc[i];
  }
  float4 a0, a1;
  if (val0) a0 = *(const float4*)g0;
  if (val1) a1 = *(const float4*)g1;
  {
    unsigned* p = (unsigned*)xs;
    for (int i = tid; i < 2 * XSHALF; i += 256) p[i] = Q0;
  }
  __syncthreads();
  if (val0) { l0[0] = quantf(a0.x); l0[1] = quantf(a0.y); l0[2] = quantf(a0.z); l0[3] = quantf(a0.w); }
  if (val1) { l1[0] = quantf(a1.x); l1[1] = quantf(a1.y); l1[2] = quantf(a1.z); l1[3] = quantf(a1.w); }
  __syncthreads();

  // ---- weights from LDS: phase ph = wv*48 + ci_local*3 + kh; 12 dwords ----
  unsigned wA[12], wB[12];
  auto LOADW = [&](unsigned* dst, int ph) {
    const uint4* wp = (const uint4*)(wl + ph * 12);
    uint4 a = wp[0], b = wp[1], c = wp[2];
    dst[0] = a.x; dst[1] = a.y; dst[2]  = a.z; dst[3]  = a.w;
    dst[4] = b.x; dst[5] = b.y; dst[6]  = b.z; dst[7]  = b.w;
    dst[8] = c.x; dst[9] = c.y; dst[10] = c.z; dst[11] = c.w;
  };

  unsigned acc[4][4];
#pragma unroll
  for (int co = 0; co < 4; ++co)
#pragma unroll
    for (int j = 0; j < 4; ++j) acc[co][j] = 0u;

  auto COMPUTE = [&](const unsigned* w, int bufsel, int kh) {
    const unsigned* rowp = &xs[bufsel][wv][r0 + kh][c0];
    uint4 x4 = *(const uint4*)rowp;        // ds_read_b128 (16B-aligned)
    uint2 x2 = *(const uint2*)(rowp + 4);  // ds_read_b64
    unsigned xv[6] = {x4.x, x4.y, x4.z, x4.w, x2.x, x2.y};
#pragma unroll
    for (int kw = 0; kw < 3; ++kw)
#pragma unroll
      for (int co = 0; co < 4; ++co) {
        unsigned ww = w[kw * 4 + co];
        acc[co][0] = sad_acc(xv[kw + 0], ww, acc[co][0]);
        acc[co][1] = sad_acc(xv[kw + 1], ww, acc[co][1]);
        acc[co][2] = sad_acc(xv[kw + 2], ww, acc[co][2]);
        acc[co][3] = sad_acc(xv[kw + 3], ww, acc[co][3]);
      }
  };

  const int PB = wv * 48;
  LOADW(wA, PB);
  for (int ci = 0; ci < 16; ci += 2) {
    const int p = PB + ci * 3;
    // prefetch planes ci+1 into regs (ci+1 <= 15 always)
    float4 b0, b1;
    if (val0) b0 = *(const float4*)(g0 + (ci + 1) * HWHW);
    if (val1) b1 = *(const float4*)(g1 + (ci + 1) * HWHW);
    LOADW(wB, p + 1);
    COMPUTE(wA, 0, 0);
    LOADW(wA, p + 2);
    COMPUTE(wB, 0, 1);
    LOADW(wB, p + 3);
    COMPUTE(wA, 0, 2);
    if (val0) { unsigned* d = l0 + XSHALF; d[0] = quantf(b0.x); d[1] = quantf(b0.y); d[2] = quantf(b0.z); d[3] = quantf(b0.w); }
    if (val1) { unsigned* d = l1 + XSHALF; d[0] = quantf(b1.x); d[1] = quantf(b1.y); d[2] = quantf(b1.z); d[3] = quantf(b1.w); }
    __syncthreads();
    // prefetch planes ci+2 (guarded)
    const bool more = (ci + 2) < 16;
    float4 e0, e1;
    if (more && val0) e0 = *(const float4*)(g0 + (ci + 2) * HWHW);
    if (more && val1) e1 = *(const float4*)(g1 + (ci + 2) * HWHW);
    LOADW(wA, p + 4);
    COMPUTE(wB, 1, 0);
    LOADW(wB, p + 5);
    COMPUTE(wA, 1, 1);
    { int pn = more ? p + 6 : PB; LOADW(wA, pn); }
    COMPUTE(wB, 1, 2);
    if (more && val0) { l0[0] = quantf(e0.x); l0[1] = quantf(e0.y); l0[2] = quantf(e0.z); l0[3] = quantf(e0.w); }
    if (more && val1) { l1[0] = quantf(e1.x); l1[1] = quantf(e1.y); l1[2] = quantf(e1.z); l1[3] = quantf(e1.w); }
    __syncthreads();
  }

  // ---- cross-wave reduction: waves 1..3 add into wave0's acc ----
  unsigned* af = &acc[0][0];
  for (int src = 1; src < 4; ++src) {
    if (wv == src) {
#pragma unroll
      for (int j = 0; j < 16; ++j) red[lane][j] = af[j];
    }
    __syncthreads();
    if (wv == 0) {
#pragma unroll
      for (int j = 0; j < 16; ++j) af[j] += red[lane][j];
    }
    __syncthreads();
  }

  // ---- wave0: convert, negate, write out, fused stats ----
  if (wv == 0) {
    const int ob = n * CHW + (rg * 8 + r0) * 32 + c0;
#pragma unroll
    for (int co = 0; co < 4; ++co) {
      float t0 = -(float)acc[co][0] * QINV;
      float t1 = -(float)acc[co][1] * QINV;
      float t2 = -(float)acc[co][2] * QINV;
      float t3 = -(float)acc[co][3] * QINV;
      *(float4*)(out + ob + (co0 + co) * HWHW) = make_float4(t0, t1, t2, t3);
      float sm = t0 + t1 + t2 + t3;
      float sq = t0 * t0 + t1 * t1 + t2 * t2 + t3 * t3;
#pragma unroll
      for (int m = 1; m < 64; m <<= 1) {
        sm += __shfl_xor(sm, m);
        sq += __shfl_xor(sq, m);
      }
      if (lane == 0) {
        atomicAdd(stats + co0 + co, sm);
        atomicAdd(stats + 64 + co0 + co, sq);
      }
    }
  }
}

// ---------------- BN (train-mode, stats given) + ReLU ----------------
__global__ __launch_bounds__(256) void bnrelu_kernel(
    const float* __restrict__ A, const float* __restrict__ stats,
    const float* __restrict__ g, const float* __restrict__ b,
    float* __restrict__ B) {
  int i = blockIdx.x * 256 + threadIdx.x;  // float4 index, 524288 total
  int c = (i >> 8) & 63;
  float mu  = stats[c] * (1.0f / NPIX);
  float var = fmaf(-mu, mu, stats[64 + c] * (1.0f / NPIX));
  float rs  = rsqrtf(var + 1e-5f);
  float ga  = g[c] * rs;
  float be  = fmaf(-mu, ga, b[c]);
  float4 v = ((const float4*)A)[i];
  v.x = fmaxf(fmaf(v.x, ga, be), 0.0f);
  v.y = fmaxf(fmaf(v.y, ga, be), 0.0f);
  v.z = fmaxf(fmaf(v.z, ga, be), 0.0f);
  v.w = fmaxf(fmaf(v.w, ga, be), 0.0f);
  ((float4*)B)[i] = v;
}

// ---------------- BN + residual + ReLU ----------------
__global__ __launch_bounds__(256) void final_kernel(
    const float* __restrict__ Cbuf, const float* __restrict__ stats,
    const float* __restrict__ g, const float* __restrict__ b,
    const float* __restrict__ xres, float* __restrict__ out) {
  int i = blockIdx.x * 256 + threadIdx.x;
  int c = (i >> 8) & 63;
  float mu  = stats[c] * (1.0f / NPIX);
  float var = fmaf(-mu, mu, stats[64 + c] * (1.0f / NPIX));
  float rs  = rsqrtf(var + 1e-5f);
  float ga  = g[c] * rs;
  float be  = fmaf(-mu, ga, b[c]);
  float4 v = ((const float4*)Cbuf)[i];
  float4 xr = ((const float4*)xres)[i];
  v.x = fmaxf(fmaf(v.x, ga, be) + xr.x, 0.0f);
  v.y = fmaxf(fmaf(v.y, ga, be) + xr.y, 0.0f);
  v.z = fmaxf(fmaf(v.z, ga, be) + xr.z, 0.0f);
  v.w = fmaxf(fmaf(v.w, ga, be) + xr.w, 0.0f);
  ((float4*)out)[i] = v;
}

extern "C" void kernel_launch(void* const* d_in, const int* in_sizes, int n_in,
                              void* d_out, int out_size, void* d_ws, size_t ws_size,
                              hipStream_t stream) {
  const float* x  = (const float*)d_in[0];
  const float* w1 = (const float*)d_in[1];
  const float* g1 = (const float*)d_in[2];
  const float* b1 = (const float*)d_in[3];
  const float* w2 = (const float*)d_in[4];
  const float* g2 = (const float*)d_in[5];
  const float* b2 = (const float*)d_in[6];
  float* outp = (float*)d_out;

  float* ws = (float*)d_ws;
  const size_t NEL = 2097152;          // 32*64*32*32
  float*    bufA  = ws;                // adder1 out, reused as adder2 out
  float*    bufB  = ws + NEL;          // bn1relu out
  unsigned* wt1   = (unsigned*)(ws + 2 * NEL);   // 36864
  unsigned* wt2   = wt1 + CH * KDIM;             // 36864
  float*    stats = (float*)(wt2 + CH * KDIM);   // 256 floats

  // 1. prep: quantize weights into per-block layout, zero stats
  prep_kernel<<<144, 256, 0, stream>>>(w1, w2, wt1, wt2, stats);

  dim3 agrid(16, 4, 32);
  // 2. adder1: x -> bufA, stats1 @ stats+0
  adder_kernel<<<agrid, 256, 0, stream>>>(x, wt1, bufA, stats);
  // 3. bn1 + relu: bufA -> bufB
  bnrelu_kernel<<<2048, 256, 0, stream>>>(bufA, stats, g1, b1, bufB);
  // 4. adder2: bufB -> bufA (reuse), stats2 @ stats+128
  adder_kernel<<<agrid, 256, 0, stream>>>(bufB, wt2, bufA, stats + 128);
  // 5. bn2 + residual + relu -> out
  final_kernel<<<2048, 256, 0, stream>>>(bufA, stats + 128, g2, b2, x, outp);
}

// Round 7
// 157.467 us; speedup vs baseline: 3.0999x; 1.0099x over previous
//
#include <hip/hip_runtime.h>

#define CH    64
#define HWHW  1024      // 32*32
#define CHW   65536     // 64*1024
#define NPIX  32768.0f  // N*H*W per channel
#define KDIM  576       // 64*3*3

#define QSCALE 524288.0f          // 2^19
#define QBIAS  4194304.5f         // 8*2^19 + 0.5 (round-to-nearest)
#define Q0     4194304u           // quant(0.0f)
#define QINV   1.9073486328125e-6f // 2^-19

__device__ __forceinline__ unsigned quantf(float x) {
  return (unsigned)fmaf(x, QSCALE, QBIAS);  // v_fma + v_cvt_u32_f32
}

// acc += |x - w| in ONE VALU instruction (all-VGPR VOP3)
__device__ __forceinline__ unsigned sad_acc(unsigned x, unsigned w, unsigned a) {
  unsigned d;
  asm("v_sad_u32 %0, %1, %2, %3" : "=v"(d) : "v"(x), "v"(w), "v"(a));
  return d;
}

// ---------------- prep: quantize weights into per-block LDS-friendly layout --
// dst layout: [cog 0..15][k 0..575][co_lo 0..3]  (2304 dwords per cog block)
__global__ __launch_bounds__(256) void prep_kernel(
    const float* __restrict__ w1, const float* __restrict__ w2,
    unsigned* __restrict__ wt1, unsigned* __restrict__ wt2,
    float* __restrict__ stats) {
  int i = blockIdx.x * 256 + threadIdx.x;
  if (i < 256) stats[i] = 0.0f;
  if (i < CH * KDIM) {
    int co = i / KDIM, k = i % KDIM;
    int dst = (co >> 2) * 2304 + k * 4 + (co & 3);
    wt1[dst] = quantf(w1[i]);
    wt2[dst] = quantf(w2[i]);
  }
}

// ---------------- adder2d + fused per-channel stats ----------------
// grid (16 cog, 4 rg, 32 n) = 2048 blocks, block 256 (4 waves).
// Wave wv sums ci in [16*wv, 16*wv+16); each wave stages its OWN x plane
// (wave-private LDS slice, single-buffered, aligned b128 writes) -> the main
// loop has ZERO barriers. Cross-wave reduce at the end (2 barriers total).
// Plane layout per wave: [10 rows][36]: col c at idx c, idx32 = right halo,
// idx33 = left halo (both constant Q0), idx34/35 pad.
__global__ __launch_bounds__(256, 6) void adder_kernel(
    const float* __restrict__ xin,    // [32][64][32][32] fp32
    const unsigned* __restrict__ wt,  // [16][576][4] quantized weights
    float* __restrict__ out,          // [32][64][32][32] fp32
    float* __restrict__ stats) {      // [0..63]=sum, [64..127]=sumsq
  const int cog  = blockIdx.x;       // 0..15
  const int rg   = blockIdx.y;       // 0..3 (8-row groups)
  const int n    = blockIdx.z;       // 0..31
  const int tid  = threadIdx.x;
  const int lane = tid & 63;
  const int wv   = __builtin_amdgcn_readfirstlane(tid >> 6);  // wave id 0..3
  const int co0  = cog * 4;
  const int r0   = lane >> 3;        // 0..7 row within group
  const int c0   = (lane & 7) * 4;   // 0,4,..,28

  // union LDS: [0..1439] xs (4 waves x [10][36]); [1440..3743] wl;
  // after main loop the whole region is reused as red[3][64][20].
  __shared__ __align__(16) unsigned lds[3840];   // 15360 B
  unsigned* xsw = lds + wv * 360;    // this wave's plane [10][36]
  unsigned* wl  = lds + 1440;        // block's weight slice (2304 dw)
  unsigned* red = lds;               // reduce scratch (aliased)

  // ---- staging descriptors: item0 = lane (rows 0..7), item1 = lane+64 ----
  const int rowA = lane >> 3, c4A = lane & 7;
  const int hrA  = rg * 8 - 1 + rowA;
  const bool vA  = (hrA >= 0) && (hrA < 32);
  const int rowB = (lane + 64) >> 3, c4B = lane & 7;   // rows 8,9 (lane<16)
  const int hrB  = rg * 8 - 1 + rowB;
  const bool vB  = (lane < 16) && (hrB >= 0) && (hrB < 32);
  const float* gbase = xin + n * CHW + (wv * 16) * HWHW;
  const float* gA = gbase + hrA * 32 + c4A * 4;
  const float* gB = gbase + hrB * 32 + c4B * 4;
  unsigned* dA = xsw + rowA * 36 + c4A * 4;
  unsigned* dB = xsw + rowB * 36 + c4B * 4;

  // ---- prologue ----
  // issue plane-0 loads first (latency hides under wl staging + Q0 fill)
  float4 a0, a1;
  if (vA) a0 = *(const float4*)gA;
  if (vB) a1 = *(const float4*)gB;
  {  // stage weights cooperatively (all 256 threads)
    const uint4* wsrc = (const uint4*)(wt + cog * 2304);
    for (int i = tid; i < 576; i += 256) ((uint4*)wl)[i] = wsrc[i];
  }
  // fill own plane with Q0 (halo cols/rows stay Q0 forever)
  for (int i = lane; i < 360; i += 64) xsw[i] = Q0;
  __syncthreads();   // wl visible to all waves
  if (vA) { uint4 q = {quantf(a0.x), quantf(a0.y), quantf(a0.z), quantf(a0.w)}; *(uint4*)dA = q; }
  if (vB) { uint4 q = {quantf(a1.x), quantf(a1.y), quantf(a1.z), quantf(a1.w)}; *(uint4*)dB = q; }

  unsigned acc[4][4];
#pragma unroll
  for (int co = 0; co < 4; ++co)
#pragma unroll
    for (int j = 0; j < 4; ++j) acc[co][j] = 0u;

  const int off0 = c0 ? (c0 - 1) : 33;   // left-halo read idx (per-lane const)

  // ---- main loop: NO barriers. Per ci: issue next-plane loads, compute
  // current plane (144 sads), then quant+write next plane (own slice). ----
  for (int ci = 0; ci < 16; ++ci) {
    const bool more = ci < 15;
    float4 b0, b1;
    if (more && vA) b0 = *(const float4*)(gA + (ci + 1) * HWHW);
    if (more && vB) b1 = *(const float4*)(gB + (ci + 1) * HWHW);

    const int ph = wv * 48 + ci * 3;
#pragma unroll
    for (int kh = 0; kh < 3; ++kh) {
      // weights: wave-uniform b128 reads (broadcast)
      const uint4* wp = (const uint4*)(wl + (ph + kh) * 12);
      uint4 wa = wp[0], wb = wp[1], wc = wp[2];
      unsigned w[12] = {wa.x, wa.y, wa.z, wa.w, wb.x, wb.y, wb.z, wb.w,
                        wc.x, wc.y, wc.z, wc.w};
      // x: aligned b128 + two b32 halo reads
      const unsigned* rp = xsw + (r0 + kh) * 36;
      uint4 x4 = *(const uint4*)(rp + c0);
      unsigned xl = rp[off0];
      unsigned xr = rp[c0 + 4];
      unsigned xv[6] = {xl, x4.x, x4.y, x4.z, x4.w, xr};
#pragma unroll
      for (int kw = 0; kw < 3; ++kw)
#pragma unroll
        for (int co = 0; co < 4; ++co) {
          unsigned ww = w[kw * 4 + co];
          acc[co][0] = sad_acc(xv[kw + 0], ww, acc[co][0]);
          acc[co][1] = sad_acc(xv[kw + 1], ww, acc[co][1]);
          acc[co][2] = sad_acc(xv[kw + 2], ww, acc[co][2]);
          acc[co][3] = sad_acc(xv[kw + 3], ww, acc[co][3]);
        }
    }
    // pin order: all reads of plane ci above, write of plane ci+1 below.
    __builtin_amdgcn_wave_barrier();
    if (more && vA) { uint4 q = {quantf(b0.x), quantf(b0.y), quantf(b0.z), quantf(b0.w)}; *(uint4*)dA = q; }
    if (more && vB) { uint4 q = {quantf(b1.x), quantf(b1.y), quantf(b1.z), quantf(b1.w)}; *(uint4*)dB = q; }
    __builtin_amdgcn_wave_barrier();
  }

  // ---- cross-wave reduction (red aliases xs+wl; 2 barriers total) ----
  __syncthreads();   // everyone done with xs/wl
  if (wv != 0) {
    unsigned* rp = red + (wv - 1) * 1280 + lane * 20;
#pragma unroll
    for (int co = 0; co < 4; ++co) {
      uint4 q = {acc[co][0], acc[co][1], acc[co][2], acc[co][3]};
      *(uint4*)(rp + co * 4) = q;
    }
  }
  __syncthreads();

  // ---- wave0: sum partials, convert, negate, write out, fused stats ----
  if (wv == 0) {
#pragma unroll
    for (int s = 0; s < 3; ++s) {
      const unsigned* rp = red + s * 1280 + lane * 20;
#pragma unroll
      for (int co = 0; co < 4; ++co) {
        uint4 q = *(const uint4*)(rp + co * 4);
        acc[co][0] += q.x; acc[co][1] += q.y; acc[co][2] += q.z; acc[co][3] += q.w;
      }
    }
    const int ob = n * CHW + (rg * 8 + r0) * 32 + c0;
#pragma unroll
    for (int co = 0; co < 4; ++co) {
      float t0 = -(float)acc[co][0] * QINV;
      float t1 = -(float)acc[co][1] * QINV;
      float t2 = -(float)acc[co][2] * QINV;
      float t3 = -(float)acc[co][3] * QINV;
      *(float4*)(out + ob + (co0 + co) * HWHW) = make_float4(t0, t1, t2, t3);
      float sm = t0 + t1 + t2 + t3;
      float sq = t0 * t0 + t1 * t1 + t2 * t2 + t3 * t3;
#pragma unroll
      for (int m = 1; m < 64; m <<= 1) {
        sm += __shfl_xor(sm, m);
        sq += __shfl_xor(sq, m);
      }
      if (lane == 0) {
        atomicAdd(stats + co0 + co, sm);
        atomicAdd(stats + 64 + co0 + co, sq);
      }
    }
  }
}

// ---------------- BN (train-mode, stats given) + ReLU ----------------
__global__ __launch_bounds__(256) void bnrelu_kernel(
    const float* __restrict__ A, const float* __restrict__ stats,
    const float* __restrict__ g, const float* __restrict__ b,
    float* __restrict__ B) {
  int i = blockIdx.x * 256 + threadIdx.x;  // float4 index, 524288 total
  int c = (i >> 8) & 63;
  float mu  = stats[c] * (1.0f / NPIX);
  float var = fmaf(-mu, mu, stats[64 + c] * (1.0f / NPIX));
  float rs  = rsqrtf(var + 1e-5f);
  float ga  = g[c] * rs;
  float be  = fmaf(-mu, ga, b[c]);
  float4 v = ((const float4*)A)[i];
  v.x = fmaxf(fmaf(v.x, ga, be), 0.0f);
  v.y = fmaxf(fmaf(v.y, ga, be), 0.0f);
  v.z = fmaxf(fmaf(v.z, ga, be), 0.0f);
  v.w = fmaxf(fmaf(v.w, ga, be), 0.0f);
  ((float4*)B)[i] = v;
}

// ---------------- BN + residual + ReLU ----------------
__global__ __launch_bounds__(256) void final_kernel(
    const float* __restrict__ Cbuf, const float* __restrict__ stats,
    const float* __restrict__ g, const float* __restrict__ b,
    const float* __restrict__ xres, float* __restrict__ out) {
  int i = blockIdx.x * 256 + threadIdx.x;
  int c = (i >> 8) & 63;
  float mu  = stats[c] * (1.0f / NPIX);
  float var = fmaf(-mu, mu, stats[64 + c] * (1.0f / NPIX));
  float rs  = rsqrtf(var + 1e-5f);
  float ga  = g[c] * rs;
  float be  = fmaf(-mu, ga, b[c]);
  float4 v = ((const float4*)Cbuf)[i];
  float4 xr = ((const float4*)xres)[i];
  v.x = fmaxf(fmaf(v.x, ga, be) + xr.x, 0.0f);
  v.y = fmaxf(fmaf(v.y, ga, be) + xr.y, 0.0f);
  v.z = fmaxf(fmaf(v.z, ga, be) + xr.z, 0.0f);
  v.w = fmaxf(fmaf(v.w, ga, be) + xr.w, 0.0f);
  ((float4*)out)[i] = v;
}

extern "C" void kernel_launch(void* const* d_in, const int* in_sizes, int n_in,
                              void* d_out, int out_size, void* d_ws, size_t ws_size,
                              hipStream_t stream) {
  const float* x  = (const float*)d_in[0];
  const float* w1 = (const float*)d_in[1];
  const float* g1 = (const float*)d_in[2];
  const float* b1 = (const float*)d_in[3];
  const float* w2 = (const float*)d_in[4];
  const float* g2 = (const float*)d_in[5];
  const float* b2 = (const float*)d_in[6];
  float* outp = (float*)d_out;

  float* ws = (float*)d_ws;
  const size_t NEL = 2097152;          // 32*64*32*32
  float*    bufA  = ws;                // adder1 out, reused as adder2 out
  float*    bufB  = ws + NEL;          // bn1relu out
  unsigned* wt1   = (unsigned*)(ws + 2 * NEL);   // 36864
  unsigned* wt2   = wt1 + CH * KDIM;             // 36864
  float*    stats = (float*)(wt2 + CH * KDIM);   // 256 floats

  // 1. prep: quantize weights into per-block layout, zero stats
  prep_kernel<<<144, 256, 0, stream>>>(w1, w2, wt1, wt2, stats);

  dim3 agrid(16, 4, 32);
  // 2. adder1: x -> bufA, stats1 @ stats+0
  adder_kernel<<<agrid, 256, 0, stream>>>(x, wt1, bufA, stats);
  // 3. bn1 + relu: bufA -> bufB
  bnrelu_kernel<<<2048, 256, 0, stream>>>(bufA, stats, g1, b1, bufB);
  // 4. adder2: bufB -> bufA (reuse), stats2 @ stats+128
  adder_kernel<<<agrid, 256, 0, stream>>>(bufB, wt2, bufA, stats + 128);
  // 5. bn2 + residual + relu -> out
  final_kernel<<<2048, 256, 0, stream>>>(bufA, stats + 128, g2, b2, x, outp);
}

// Round 8
// 145.094 us; speedup vs baseline: 3.3643x; 1.0853x over previous
//
#include <hip/hip_runtime.h>

#define CH    64
#define HWHW  1024      // 32*32
#define CHW   65536     // 64*1024
#define NPIX  32768.0f  // N*H*W per channel

#define QS16   4096.0f            // 2^12 quant scale
#define QB16   32768.5f           // 8*4096 bias + 0.5 round
#define Q0P    0x80008000u        // quant16(0) packed in both halves
#define QINV16 2.44140625e-4f     // 2^-12

__device__ __forceinline__ unsigned q16(float x) {
  unsigned u = (unsigned)fmaf(x, QS16, QB16);   // negative saturates to 0
  return u > 65535u ? 65535u : u;
}
__device__ __forceinline__ unsigned q16pk(float lo, float hi) {
  return q16(lo) | (q16(hi) << 16);
}

// acc += |x.lo16-w.lo16| + |x.hi16-w.hi16| : TWO terms per VALU instruction
__device__ __forceinline__ unsigned sad16(unsigned x, unsigned w, unsigned a) {
  unsigned d;
  asm("v_sad_u16 %0, %1, %2, %3" : "=v"(d) : "v"(x), "v"(w), "v"(a));
  return d;
}

// ---------------- prep: quantize+pack weights (2 ci planes / u32) ----------
// dst u32 idx = cog*1152 + wv*288 + cp*36 + kh*12 + kw*4 + colo
// lo16 = w[co][wv*16+2cp][kh][kw], hi16 = w[co][wv*16+2cp+1][kh][kw]
__global__ __launch_bounds__(256) void prep_kernel(
    const float* __restrict__ w1, const float* __restrict__ w2,
    unsigned* __restrict__ wt1, unsigned* __restrict__ wt2,
    float* __restrict__ stats) {
  int j = blockIdx.x * 256 + threadIdx.x;
  if (j < 256) stats[j] = 0.0f;
  if (j < 18432) {
    int colo = j & 3;
    int t = j >> 2;
    int kw = t % 3; t /= 3;
    int kh = t % 3; t /= 3;
    int cp = t & 7; t >>= 3;
    int wv = t & 3; int cog = t >> 2;
    int co  = cog * 4 + colo;
    int cil = wv * 16 + cp * 2;
    int slo = co * 576 + cil * 9 + kh * 3 + kw;   // [co][ci][kh][kw]
    wt1[j] = q16pk(w1[slo], w1[slo + 9]);
    wt2[j] = q16pk(w2[slo], w2[slo + 9]);
  }
}

// ---------------- adder2d + fused per-channel stats ----------------
// grid (16 cog, 4 rg, 32 n) = 2048 blocks, block 256 (4 waves).
// Wave wv sums ci in [16*wv, 16*wv+16) as 8 packed pairs; wave-private
// single-buffered x plane (barrier-free main loop, R7); x layout = R5's
// proven conflict-free pattern: odd stride 37, col c at idx c+1, all-b32.
__global__ __launch_bounds__(256, 6) void adder_kernel(
    const float* __restrict__ xin,    // [32][64][32][32] fp32
    const unsigned* __restrict__ wt,  // [16][1152] packed weights
    float* __restrict__ out,          // [32][64][32][32] fp32
    float* __restrict__ stats) {      // [0..63]=sum, [64..127]=sumsq
  const int cog  = blockIdx.x;       // 0..15
  const int rg   = blockIdx.y;       // 0..3 (8-row groups)
  const int n    = blockIdx.z;       // 0..31
  const int tid  = threadIdx.x;
  const int lane = tid & 63;
  const int wv   = __builtin_amdgcn_readfirstlane(tid >> 6);  // wave 0..3
  const int co0  = cog * 4;
  const int r0   = lane >> 3;        // 0..7 row within group
  const int c0   = (lane & 7) * 4;   // 0,4,..,28

  // union LDS: [0..1479] xs (4 waves x [10][37] packed-pair planes);
  // [1480..2631] wl (1152 packed w); reduce scratch red[3][64][20] aliases all.
  __shared__ __align__(16) unsigned lds[3840];   // 15360 B
  unsigned* xsw = lds + wv * 370;    // this wave's plane [10][37]
  unsigned* wl  = lds + 1480;
  unsigned* red = lds;

  // ---- staging descriptors: itemA = rows 0..7 (all lanes), itemB = rows 8,9
  const int rowA = lane >> 3, c4A = lane & 7;
  const int hrA  = rg * 8 - 1 + rowA;
  const bool vA  = (hrA >= 0) && (hrA < 32);
  const int rowB = (lane + 64) >> 3;             // 8 or 9 (lane<16)
  const int hrB  = rg * 8 - 1 + rowB;
  const bool vB  = (lane < 16) && (hrB >= 0) && (hrB < 32);
  const float* gbase = xin + n * CHW + (wv * 16) * HWHW;
  const float* gA = gbase + hrA * 32 + c4A * 4;
  const float* gB = gbase + hrB * 32 + c4A * 4;
  unsigned* dA = xsw + rowA * 37 + 1 + c4A * 4;
  unsigned* dB = xsw + rowB * 37 + 1 + c4A * 4;

  // ---- prologue: issue pair-0 loads, stage weights, Q0P fill ----
  float4 a0, a1, b0, b1;
  if (vA) { a0 = *(const float4*)gA; a1 = *(const float4*)(gA + HWHW); }
  if (vB) { b0 = *(const float4*)gB; b1 = *(const float4*)(gB + HWHW); }
  {
    const uint4* wsrc = (const uint4*)(wt + cog * 1152);
    for (int i = tid; i < 288; i += 256) ((uint4*)wl)[i] = wsrc[i];
  }
  for (int i = lane; i < 370; i += 64) xsw[i] = Q0P;   // halos stay Q0P
  __syncthreads();   // wl visible to all waves
  if (vA) { dA[0] = q16pk(a0.x, a1.x); dA[1] = q16pk(a0.y, a1.y);
            dA[2] = q16pk(a0.z, a1.z); dA[3] = q16pk(a0.w, a1.w); }
  if (vB) { dB[0] = q16pk(b0.x, b1.x); dB[1] = q16pk(b0.y, b1.y);
            dB[2] = q16pk(b0.z, b1.z); dB[3] = q16pk(b0.w, b1.w); }

  unsigned acc[4][4];
#pragma unroll
  for (int co = 0; co < 4; ++co)
#pragma unroll
    for (int j = 0; j < 4; ++j) acc[co][j] = 0u;

  // ---- main loop: 8 ci-pairs, NO barriers. ----
  for (int cp = 0; cp < 8; ++cp) {
    const bool more = cp < 7;
    float4 pa0, pa1, pb0, pb1;
    if (more && vA) { pa0 = *(const float4*)(gA + (2 * cp + 2) * HWHW);
                      pa1 = *(const float4*)(gA + (2 * cp + 3) * HWHW); }
    if (more && vB) { pb0 = *(const float4*)(gB + (2 * cp + 2) * HWHW);
                      pb1 = *(const float4*)(gB + (2 * cp + 3) * HWHW); }

    const unsigned* wpb = wl + wv * 288 + cp * 36;
#pragma unroll
    for (int kh = 0; kh < 3; ++kh) {
      // weights: wave-uniform b128 broadcasts (conflict-free)
      const uint4* wp = (const uint4*)(wpb + kh * 12);
      uint4 wa = wp[0], wb = wp[1], wc = wp[2];
      unsigned w[12] = {wa.x, wa.y, wa.z, wa.w, wb.x, wb.y, wb.z, wb.w,
                        wc.x, wc.y, wc.z, wc.w};
      // x: 6 b32 reads, odd-stride layout (R5-proven conflict-free)
      const unsigned* rp = xsw + (r0 + kh) * 37 + c0;
      unsigned xv[6];
#pragma unroll
      for (int j = 0; j < 6; ++j) xv[j] = rp[j];
#pragma unroll
      for (int kw = 0; kw < 3; ++kw)
#pragma unroll
        for (int co = 0; co < 4; ++co) {
          unsigned ww = w[kw * 4 + co];
          acc[co][0] = sad16(xv[kw + 0], ww, acc[co][0]);
          acc[co][1] = sad16(xv[kw + 1], ww, acc[co][1]);
          acc[co][2] = sad16(xv[kw + 2], ww, acc[co][2]);
          acc[co][3] = sad16(xv[kw + 3], ww, acc[co][3]);
        }
    }
    // pin order: reads of pair cp above, write of pair cp+1 below
    __builtin_amdgcn_wave_barrier();
    if (more && vA) { dA[0] = q16pk(pa0.x, pa1.x); dA[1] = q16pk(pa0.y, pa1.y);
                      dA[2] = q16pk(pa0.z, pa1.z); dA[3] = q16pk(pa0.w, pa1.w); }
    if (more && vB) { dB[0] = q16pk(pb0.x, pb1.x); dB[1] = q16pk(pb0.y, pb1.y);
                      dB[2] = q16pk(pb0.z, pb1.z); dB[3] = q16pk(pb0.w, pb1.w); }
    __builtin_amdgcn_wave_barrier();
  }

  // ---- cross-wave reduction (red aliases xs+wl) ----
  __syncthreads();
  if (wv != 0) {
    unsigned* rp = red + (wv - 1) * 1280 + lane * 20;
#pragma unroll
    for (int co = 0; co < 4; ++co) {
      uint4 q = {acc[co][0], acc[co][1], acc[co][2], acc[co][3]};
      *(uint4*)(rp + co * 4) = q;
    }
  }
  __syncthreads();

  // ---- wave0: sum partials, convert, negate, write out, fused stats ----
  if (wv == 0) {
#pragma unroll
    for (int s = 0; s < 3; ++s) {
      const unsigned* rp = red + s * 1280 + lane * 20;
#pragma unroll
      for (int co = 0; co < 4; ++co) {
        uint4 q = *(const uint4*)(rp + co * 4);
        acc[co][0] += q.x; acc[co][1] += q.y; acc[co][2] += q.z; acc[co][3] += q.w;
      }
    }
    const int ob = n * CHW + (rg * 8 + r0) * 32 + c0;
#pragma unroll
    for (int co = 0; co < 4; ++co) {
      float t0 = -(float)acc[co][0] * QINV16;
      float t1 = -(float)acc[co][1] * QINV16;
      float t2 = -(float)acc[co][2] * QINV16;
      float t3 = -(float)acc[co][3] * QINV16;
      *(float4*)(out + ob + (co0 + co) * HWHW) = make_float4(t0, t1, t2, t3);
      float sm = t0 + t1 + t2 + t3;
      float sq = t0 * t0 + t1 * t1 + t2 * t2 + t3 * t3;
#pragma unroll
      for (int m = 1; m < 64; m <<= 1) {
        sm += __shfl_xor(sm, m);
        sq += __shfl_xor(sq, m);
      }
      if (lane == 0) {
        atomicAdd(stats + co0 + co, sm);
        atomicAdd(stats + 64 + co0 + co, sq);
      }
    }
  }
}

// ---------------- BN (train-mode, stats given) + ReLU ----------------
__global__ __launch_bounds__(256) void bnrelu_kernel(
    const float* __restrict__ A, const float* __restrict__ stats,
    const float* __restrict__ g, const float* __restrict__ b,
    float* __restrict__ B) {
  int i = blockIdx.x * 256 + threadIdx.x;  // float4 index, 524288 total
  int c = (i >> 8) & 63;
  float mu  = stats[c] * (1.0f / NPIX);
  float var = fmaf(-mu, mu, stats[64 + c] * (1.0f / NPIX));
  float rs  = rsqrtf(var + 1e-5f);
  float ga  = g[c] * rs;
  float be  = fmaf(-mu, ga, b[c]);
  float4 v = ((const float4*)A)[i];
  v.x = fmaxf(fmaf(v.x, ga, be), 0.0f);
  v.y = fmaxf(fmaf(v.y, ga, be), 0.0f);
  v.z = fmaxf(fmaf(v.z, ga, be), 0.0f);
  v.w = fmaxf(fmaf(v.w, ga, be), 0.0f);
  ((float4*)B)[i] = v;
}

// ---------------- BN + residual + ReLU ----------------
__global__ __launch_bounds__(256) void final_kernel(
    const float* __restrict__ Cbuf, const float* __restrict__ stats,
    const float* __restrict__ g, const float* __restrict__ b,
    const float* __restrict__ xres, float* __restrict__ out) {
  int i = blockIdx.x * 256 + threadIdx.x;
  int c = (i >> 8) & 63;
  float mu  = stats[c] * (1.0f / NPIX);
  float var = fmaf(-mu, mu, stats[64 + c] * (1.0f / NPIX));
  float rs  = rsqrtf(var + 1e-5f);
  float ga  = g[c] * rs;
  float be  = fmaf(-mu, ga, b[c]);
  float4 v = ((const float4*)Cbuf)[i];
  float4 xr = ((const float4*)xres)[i];
  v.x = fmaxf(fmaf(v.x, ga, be) + xr.x, 0.0f);
  v.y = fmaxf(fmaf(v.y, ga, be) + xr.y, 0.0f);
  v.z = fmaxf(fmaf(v.z, ga, be) + xr.z, 0.0f);
  v.w = fmaxf(fmaf(v.w, ga, be) + xr.w, 0.0f);
  ((float4*)out)[i] = v;
}

extern "C" void kernel_launch(void* const* d_in, const int* in_sizes, int n_in,
                              void* d_out, int out_size, void* d_ws, size_t ws_size,
                              hipStream_t stream) {
  const float* x  = (const float*)d_in[0];
  const float* w1 = (const float*)d_in[1];
  const float* g1 = (const float*)d_in[2];
  const float* b1 = (const float*)d_in[3];
  const float* w2 = (const float*)d_in[4];
  const float* g2 = (const float*)d_in[5];
  const float* b2 = (const float*)d_in[6];
  float* outp = (float*)d_out;

  float* ws = (float*)d_ws;
  const size_t NEL = 2097152;          // 32*64*32*32
  float*    bufA  = ws;                // adder1 out, reused as adder2 out
  float*    bufB  = ws + NEL;          // bn1relu out
  unsigned* wt1   = (unsigned*)(ws + 2 * NEL);   // 18432 u32
  unsigned* wt2   = wt1 + 18432;                 // 18432 u32
  float*    stats = (float*)(wt2 + 18432);       // 256 floats

  // 1. prep: quantize+pack weights, zero stats
  prep_kernel<<<72, 256, 0, stream>>>(w1, w2, wt1, wt2, stats);

  dim3 agrid(16, 4, 32);
  // 2. adder1: x -> bufA, stats1 @ stats+0
  adder_kernel<<<agrid, 256, 0, stream>>>(x, wt1, bufA, stats);
  // 3. bn1 + relu: bufA -> bufB
  bnrelu_kernel<<<2048, 256, 0, stream>>>(bufA, stats, g1, b1, bufB);
  // 4. adder2: bufB -> bufA (reuse), stats2 @ stats+128
  adder_kernel<<<agrid, 256, 0, stream>>>(bufB, wt2, bufA, stats + 128);
  // 5. bn2 + residual + relu -> out
  final_kernel<<<2048, 256, 0, stream>>>(bufA, stats + 128, g2, b2, x, outp);
}